// Round 4
// baseline (653.549 us; speedup 1.0000x reference)
//
#include <hip/hip_runtime.h>
#include <hip/hip_bf16.h>

#define N_NODES 50000
#define N_EDGES 800000
#define FD 128
#define N_GRAPHS 256

// ---------------------------------------------------------------- CSR build
__global__ void count_deg_k(const int* __restrict__ src, int* __restrict__ cnt, int E) {
    int e = blockIdx.x * blockDim.x + threadIdx.x;
    if (e < E) atomicAdd(&cnt[src[e]], 1);
}

__global__ __launch_bounds__(256) void scan1_k(const int* __restrict__ cnt,
                                               int* __restrict__ bsum, int M) {
    int i = blockIdx.x * 256 + threadIdx.x;
    int v = (i < M) ? cnt[i] : 0;
    __shared__ int l[256];
    l[threadIdx.x] = v;
    __syncthreads();
    for (int s = 128; s > 0; s >>= 1) {
        if (threadIdx.x < s) l[threadIdx.x] += l[threadIdx.x + s];
        __syncthreads();
    }
    if (threadIdx.x == 0) bsum[blockIdx.x] = l[0];
}

__global__ __launch_bounds__(256) void scan2_k(int* __restrict__ bsum, int NB) {
    int tid = threadIdx.x;
    int v = (tid < NB) ? bsum[tid] : 0;
    __shared__ int l[256];
    l[tid] = v;
    __syncthreads();
    for (int off = 1; off < 256; off <<= 1) {
        int t = (tid >= off) ? l[tid - off] : 0;
        __syncthreads();
        l[tid] += t;
        __syncthreads();
    }
    if (tid < NB) bsum[tid] = l[tid] - v;   // exclusive
}

__global__ __launch_bounds__(256) void scan3_k(const int* __restrict__ cnt,
                                               const int* __restrict__ bsum,
                                               int* __restrict__ offs,
                                               int* __restrict__ cur, int M) {
    int i = blockIdx.x * 256 + threadIdx.x;
    int tid = threadIdx.x;
    int v = (i < M) ? cnt[i] : 0;
    __shared__ int l[256];
    l[tid] = v;
    __syncthreads();
    for (int off = 1; off < 256; off <<= 1) {
        int t = (tid >= off) ? l[tid - off] : 0;
        __syncthreads();
        l[tid] += t;
        __syncthreads();
    }
    int excl = l[tid] - v + bsum[blockIdx.x];
    if (i < M) { offs[i] = excl; cur[i] = excl; }
    if (i == M - 1) offs[M] = excl + v;
}

__global__ void fill_csr_k(const int* __restrict__ src, const int* __restrict__ dst,
                           int* __restrict__ cur, int* __restrict__ col, int E) {
    int e = blockIdx.x * blockDim.x + threadIdx.x;
    if (e < E) {
        int p = atomicAdd(&cur[src[e]], 1);
        col[p] = dst[e];
    }
}

// ---------------------------------------------------------------- GEMM + BN-in + attention dots
// H = (X*scale+shift) @ W ; es/ed = H@a ; H stored bf16 in 4 quarter-planes:
// Hq[q*M*32 + node*32 + f]  (f = 0..31, global feature = q*32+f)
__global__ __launch_bounds__(256) void gemm_bn_dots_k(const float* __restrict__ X,
                                                      const float* __restrict__ W,
                                                      const float* __restrict__ scale,
                                                      const float* __restrict__ shift,
                                                      const float* __restrict__ avec,
                                                      __hip_bfloat16* __restrict__ Hq,
                                                      float* __restrict__ es,
                                                      float* __restrict__ ed, int M) {
    __shared__ float As[16][132];
    __shared__ float Bs[16][128];
    __shared__ float sc[128], sh[128], sa_s[128], sa_d[128];
    int tid = threadIdx.x;
    if (tid < 128) {
        sc[tid] = scale[tid]; sh[tid] = shift[tid];
        sa_s[tid] = avec[tid]; sa_d[tid] = avec[128 + tid];
    }
    __syncthreads();
    int row0 = blockIdx.x * 128;
    int tc = tid & 15, tr = tid >> 4;
    float acc[8][8];
#pragma unroll
    for (int i = 0; i < 8; i++)
#pragma unroll
        for (int j = 0; j < 8; j++) acc[i][j] = 0.f;

    for (int k0 = 0; k0 < 128; k0 += 16) {
        int r = tid >> 2;
        int kk = (tid & 3) * 4;
#pragma unroll
        for (int half = 0; half < 2; half++) {
            int rr = r + half * 64;
            int grow = row0 + rr;
            float4 v = make_float4(0.f, 0.f, 0.f, 0.f);
            if (grow < M) v = *(const float4*)&X[(size_t)grow * FD + k0 + kk];
            v.x = v.x * sc[k0 + kk]     + sh[k0 + kk];
            v.y = v.y * sc[k0 + kk + 1] + sh[k0 + kk + 1];
            v.z = v.z * sc[k0 + kk + 2] + sh[k0 + kk + 2];
            v.w = v.w * sc[k0 + kk + 3] + sh[k0 + kk + 3];
            As[kk][rr] = v.x; As[kk + 1][rr] = v.y; As[kk + 2][rr] = v.z; As[kk + 3][rr] = v.w;
        }
        int kb = tid >> 5;
        int cb = (tid & 31) * 4;
#pragma unroll
        for (int half = 0; half < 2; half++) {
            int kr = kb + half * 8;
            *(float4*)&Bs[kr][cb] = *(const float4*)&W[(size_t)(k0 + kr) * FD + cb];
        }
        __syncthreads();
#pragma unroll
        for (int k = 0; k < 16; k++) {
            float a[8], b[8];
#pragma unroll
            for (int i = 0; i < 8; i++) a[i] = As[k][tr * 8 + i];
#pragma unroll
            for (int j = 0; j < 8; j++) b[j] = Bs[k][tc * 8 + j];
#pragma unroll
            for (int i = 0; i < 8; i++)
#pragma unroll
                for (int j = 0; j < 8; j++) acc[i][j] += a[i] * b[j];
        }
        __syncthreads();
    }

    // Epilogue: attention dots (16-lane butterfly over tc) + bf16 quarter-plane store.
#pragma unroll
    for (int i = 0; i < 8; i++) {
        int grow = row0 + tr * 8 + i;
        float ps = 0.f, pd = 0.f;
#pragma unroll
        for (int j = 0; j < 8; j++) {
            ps += acc[i][j] * sa_s[tc * 8 + j];
            pd += acc[i][j] * sa_d[tc * 8 + j];
        }
#pragma unroll
        for (int o = 8; o > 0; o >>= 1) { ps += __shfl_xor(ps, o); pd += __shfl_xor(pd, o); }
        if (grow < M) {
            if (tc == 0) { es[grow] = ps; ed[grow] = pd; }
            union { uint4 q; __hip_bfloat16 h[8]; } p;
#pragma unroll
            for (int j = 0; j < 8; j++) p.h[j] = __float2bfloat16(acc[i][j]);
            int qq = tc >> 2;
            *(uint4*)&Hq[(size_t)qq * M * 32 + (size_t)grow * 32 + (tc & 3) * 8] = p.q;
        }
    }
}

// ---------------------------------------------------------------- per-edge ee + rowsum (wave per node)
__global__ __launch_bounds__(256) void ee_k(const float* __restrict__ es_,
                                            const float* __restrict__ ed_,
                                            const int* __restrict__ offs,
                                            const int* __restrict__ col,
                                            float* __restrict__ ee,
                                            float* __restrict__ rowsum, int M) {
    int wave = (blockIdx.x * blockDim.x + threadIdx.x) >> 6;
    int lane = threadIdx.x & 63;
    if (wave >= M) return;
    int s0 = offs[wave], s1 = offs[wave + 1];
    float es = es_[wave];
    float rs = 0.f;
    for (int base = s0; base < s1; base += 64) {
        int m = s1 - base; if (m > 64) m = 64;
        if (lane < m) {
            int d = col[base + lane];
            float e = es + ed_[d];
            float lr = e > 0.f ? e : 0.2f * e;
            float v = __expf(-lr);
            ee[base + lane] = v;
            rs += v;
        }
    }
#pragma unroll
    for (int o = 32; o > 0; o >>= 1) rs += __shfl_xor(rs, o);
    if (lane == 0) rowsum[wave] = rs;
}

// ---------------------------------------------------------------- aggregation (wave per node-quarter)
// quarter pinned to an XCD pair via blockIdx%8 so each XCD's L2 only caches one 3.2 MB plane.
__global__ __launch_bounds__(256) void agg_q_k(const __hip_bfloat16* __restrict__ Hq,
                                               const float* __restrict__ ee,
                                               const float* __restrict__ rowsum,
                                               const int* __restrict__ offs,
                                               const int* __restrict__ col,
                                               float* __restrict__ Out, int M) {
    int b = blockIdx.x;
    int q = (b & 7) >> 1;
    int i = ((b >> 3) << 1) | (b & 1);
    int node = i * 4 + (threadIdx.x >> 6);
    if (node >= M) return;
    int lane = threadIdx.x & 63;
    int g = lane >> 3;        // edge group 0..7
    int fp = lane & 7;        // feature quad: quarter-features fp*4 .. fp*4+4
    const __hip_bfloat16* plane = Hq + (size_t)q * M * 32;
    int s0 = offs[node], s1 = offs[node + 1];
    float4 acc = make_float4(0.f, 0.f, 0.f, 0.f);
    for (int base = s0; base < s1; base += 64) {
        int m = s1 - base; if (m > 64) m = 64;
        int d = 0; float w = 0.f;
        if (lane < m) { d = col[base + lane]; w = ee[base + lane]; }
        for (int j = 0; j < m; j += 8) {
            int   dj = __shfl(d, j + g);
            float wj = __shfl(w, j + g);
            uint2 raw = *(const uint2*)&plane[(size_t)dj * 32 + fp * 4];
            __hip_bfloat162 p0 = *(__hip_bfloat162*)&raw.x;
            __hip_bfloat162 p1 = *(__hip_bfloat162*)&raw.y;
            acc.x += wj * __low2float(p0);
            acc.y += wj * __high2float(p0);
            acc.z += wj * __low2float(p1);
            acc.w += wj * __high2float(p1);
        }
    }
#pragma unroll
    for (int o = 8; o < 64; o <<= 1) {
        acc.x += __shfl_xor(acc.x, o);
        acc.y += __shfl_xor(acc.y, o);
        acc.z += __shfl_xor(acc.z, o);
        acc.w += __shfl_xor(acc.w, o);
    }
    if (g == 0) {
        float inv = 1.f / (rowsum[node] + 1e-16f);
        float4 v;
        v.x = acc.x * inv; v.y = acc.y * inv; v.z = acc.z * inv; v.w = acc.w * inv;
        v.x = v.x > 0.f ? v.x : (__expf(v.x) - 1.f);
        v.y = v.y > 0.f ? v.y : (__expf(v.y) - 1.f);
        v.z = v.z > 0.f ? v.z : (__expf(v.z) - 1.f);
        v.w = v.w > 0.f ? v.w : (__expf(v.w) - 1.f);
        *(float4*)&Out[(size_t)node * FD + q * 32 + fp * 4] = v;
    }
}

// ---------------------------------------------------------------- BN stats / finalize
__global__ void bnstats_k(const float* __restrict__ X, float* __restrict__ sums,
                          float* __restrict__ sumsq, int M) {
    int f = threadIdx.x & 127;
    int half = threadIdx.x >> 7;
    float s1 = 0.f, s2 = 0.f;
    for (int r = blockIdx.x * 2 + half; r < M; r += gridDim.x * 2) {
        float v = X[(size_t)r * FD + f];
        s1 += v; s2 += v * v;
    }
    __shared__ float l1[256], l2[256];
    l1[threadIdx.x] = s1; l2[threadIdx.x] = s2;
    __syncthreads();
    if (half == 0) {
        atomicAdd(&sums[f], l1[f] + l1[f + 128]);
        atomicAdd(&sumsq[f], l2[f] + l2[f + 128]);
    }
}

__global__ void init_affine_k(float* scale, float* shift, float* sums, float* sumsq) {
    int f = threadIdx.x;
    scale[f] = 1.f; shift[f] = 0.f; sums[f] = 0.f; sumsq[f] = 0.f;
}

__global__ void bnfinal_k(float* sums, float* sumsq, const float* __restrict__ g,
                          const float* __restrict__ b, float* scale, float* shift, float invN) {
    int f = threadIdx.x;
    float mu = sums[f] * invN;
    float var = sumsq[f] * invN - mu * mu;
    float sc = g[f] * rsqrtf(var + 1e-5f);
    scale[f] = sc;
    shift[f] = b[f] - mu * sc;
    sums[f] = 0.f; sumsq[f] = 0.f;   // ready for next stats pass
}

// ---------------------------------------------------------------- pooling (sorted graph ids)
__global__ void pool_k(const float* __restrict__ X, const int* __restrict__ gi,
                       float* __restrict__ pooled, int M) {
    int f = threadIdx.x & 127;
    int half = threadIdx.x >> 7;
    int r0 = blockIdx.x * 128 + half;
    int rend = min(blockIdx.x * 128 + 128, M);
    int curg = -1; float acc = 0.f;
    for (int r = r0; r < rend; r += 2) {
        int g = gi[r];
        if (g != curg) {
            if (curg >= 0) atomicAdd(&pooled[(size_t)curg * FD + f], acc);
            curg = g; acc = 0.f;
        }
        acc += X[(size_t)r * FD + f];
    }
    if (curg >= 0) atomicAdd(&pooled[(size_t)curg * FD + f], acc);
}

// ---------------------------------------------------------------- small MLP
__global__ void fc_relu_k(const float* __restrict__ X, const float* __restrict__ Wt,
                          const float* __restrict__ b, float* __restrict__ Y,
                          int K, int Ncols) {
    int g = blockIdx.x;
    int j = threadIdx.x;
    extern __shared__ float xrow[];
    for (int k = threadIdx.x; k < K; k += blockDim.x) xrow[k] = X[(size_t)g * K + k];
    __syncthreads();
    float s = b[j];
    for (int k = 0; k < K; k++) s += xrow[k] * Wt[(size_t)k * Ncols + j];
    Y[(size_t)g * Ncols + j] = fmaxf(s, 0.f);
}

__global__ void fc3_k(const float* __restrict__ X, const float* __restrict__ W,
                      const float* __restrict__ b, float* __restrict__ out) {
    int g = blockIdx.x;
    int l = threadIdx.x;
    float2 x2 = ((const float2*)X)[g * 64 + l];
    float s0 = x2.x * W[(2 * l) * 2]     + x2.y * W[(2 * l + 1) * 2];
    float s1 = x2.x * W[(2 * l) * 2 + 1] + x2.y * W[(2 * l + 1) * 2 + 1];
#pragma unroll
    for (int o = 32; o > 0; o >>= 1) { s0 += __shfl_xor(s0, o); s1 += __shfl_xor(s1, o); }
    if (l == 0) { out[g * 2] = s0 + b[0]; out[g * 2 + 1] = s1 + b[1]; }
}

// ---------------------------------------------------------------- launcher
extern "C" void kernel_launch(void* const* d_in, const int* in_sizes, int n_in,
                              void* d_out, int out_size, void* d_ws, size_t ws_size,
                              hipStream_t stream) {
    const int*   adj  = (const int*)d_in[0];
    const float* xin  = (const float*)d_in[1];
    const int*   gi   = (const int*)d_in[2];
    const float* W1   = (const float*)d_in[4];
    const float* a1   = (const float*)d_in[5];
    const float* bn2g = (const float*)d_in[6];
    const float* bn2b = (const float*)d_in[7];
    const float* W2   = (const float*)d_in[8];
    const float* a2   = (const float*)d_in[9];
    const float* bn3g = (const float*)d_in[10];
    const float* bn3b = (const float*)d_in[11];
    const float* W3   = (const float*)d_in[12];
    const float* a3   = (const float*)d_in[13];
    const float* fc1w = (const float*)d_in[14];
    const float* fc1b = (const float*)d_in[15];
    const float* fc2w = (const float*)d_in[16];
    const float* fc2b = (const float*)d_in[17];
    const float* fc3w = (const float*)d_in[18];
    const float* fc3b = (const float*)d_in[19];
    float* out = (float*)d_out;

    const int N = N_NODES, E = N_EDGES, G = N_GRAPHS;

    float* buf1   = (float*)d_ws;                 // [N,128] fp32 (agg out / gemm in)
    __hip_bfloat16* Hq = (__hip_bfloat16*)(buf1 + (size_t)N * FD);  // 4 planes [N,32] bf16
    float* es     = (float*)(Hq + (size_t)N * FD); // [N]
    float* ed     = es + N;                       // [N]
    float* rowsum = ed + N;                       // [N]
    float* eebuf  = rowsum + N;                   // [E]
    float* scale  = eebuf + E;                    // [128]
    float* shift  = scale + FD;                   // [128]
    float* sums   = shift + FD;                   // [128]
    float* sumsq  = sums + FD;                    // [128]
    float* pooled = sumsq + FD;                   // [G,128]
    float* t1     = pooled + (size_t)G * FD;      // [G,256]
    float* t2     = t1 + (size_t)G * 256;         // [G,128]
    int*   degcnt = (int*)(t2 + (size_t)G * FD);  // [N]
    int*   offs   = degcnt + N;                   // [N+1]
    int*   cur    = offs + (N + 1);               // [N]
    int*   col    = cur + N;                      // [E]
    int*   bsum   = col + E;                      // [256]

    const int* srcp = adj;
    const int* dstp = adj + E;

    const int NB = (N + 255) / 256;

    // ---- CSR build (once; reused by all 3 layers)
    hipMemsetAsync(degcnt, 0, (size_t)N * sizeof(int), stream);
    count_deg_k<<<(E + 255) / 256, 256, 0, stream>>>(srcp, degcnt, E);
    scan1_k<<<NB, 256, 0, stream>>>(degcnt, bsum, N);
    scan2_k<<<1, 256, 0, stream>>>(bsum, NB);
    scan3_k<<<NB, 256, 0, stream>>>(degcnt, bsum, offs, cur, N);
    fill_csr_k<<<(E + 255) / 256, 256, 0, stream>>>(srcp, dstp, cur, col, E);
    init_affine_k<<<1, 128, 0, stream>>>(scale, shift, sums, sumsq);

    const int gemm_grid = (N + 127) / 128;
    const int wave_grid = (N + 3) / 4;
    // agg grid: 8 * halfI blocks; block b -> quarter (b%8)>>1, node group ((b>>3)*2 + (b&1))*4
    const int halfI = ((N + 3) / 4 + 1) / 2;
    const int aggq_grid = 8 * halfI;
    const float invN = 1.0f / (float)N;

    // ---- layer 1
    gemm_bn_dots_k<<<gemm_grid, 256, 0, stream>>>(xin, W1, scale, shift, a1, Hq, es, ed, N);
    ee_k<<<wave_grid, 256, 0, stream>>>(es, ed, offs, col, eebuf, rowsum, N);
    agg_q_k<<<aggq_grid, 256, 0, stream>>>(Hq, eebuf, rowsum, offs, col, buf1, N);
    bnstats_k<<<256, 256, 0, stream>>>(buf1, sums, sumsq, N);
    bnfinal_k<<<1, 128, 0, stream>>>(sums, sumsq, bn2g, bn2b, scale, shift, invN);

    // ---- layer 2 (BN fused into GEMM A-load)
    gemm_bn_dots_k<<<gemm_grid, 256, 0, stream>>>(buf1, W2, scale, shift, a2, Hq, es, ed, N);
    ee_k<<<wave_grid, 256, 0, stream>>>(es, ed, offs, col, eebuf, rowsum, N);
    agg_q_k<<<aggq_grid, 256, 0, stream>>>(Hq, eebuf, rowsum, offs, col, buf1, N);
    bnstats_k<<<256, 256, 0, stream>>>(buf1, sums, sumsq, N);
    bnfinal_k<<<1, 128, 0, stream>>>(sums, sumsq, bn3g, bn3b, scale, shift, invN);

    // ---- layer 3
    gemm_bn_dots_k<<<gemm_grid, 256, 0, stream>>>(buf1, W3, scale, shift, a3, Hq, es, ed, N);
    ee_k<<<wave_grid, 256, 0, stream>>>(es, ed, offs, col, eebuf, rowsum, N);
    agg_q_k<<<aggq_grid, 256, 0, stream>>>(Hq, eebuf, rowsum, offs, col, buf1, N);

    // ---- pooling + MLP
    hipMemsetAsync(pooled, 0, (size_t)G * FD * sizeof(float), stream);
    pool_k<<<(N + 127) / 128, 256, 0, stream>>>(buf1, gi, pooled, N);
    fc_relu_k<<<G, 256, FD * sizeof(float), stream>>>(pooled, fc1w, fc1b, t1, FD, 256);
    fc_relu_k<<<G, 128, 256 * sizeof(float), stream>>>(t1, fc2w, fc2b, t2, 256, FD);
    fc3_k<<<G, 64, 0, stream>>>(t2, fc3w, fc3b, out);
}

// Round 5
// 550.465 us; speedup vs baseline: 1.1873x; 1.1873x over previous
//
#include <hip/hip_runtime.h>
#include <hip/hip_bf16.h>

#define N_NODES 50000
#define N_EDGES 800000
#define FD 128
#define N_GRAPHS 256

// ---------------------------------------------------------------- CSR build
__global__ void count_deg_k(const int* __restrict__ src, int* __restrict__ cnt, int E) {
    int e = blockIdx.x * blockDim.x + threadIdx.x;
    if (e < E) atomicAdd(&cnt[src[e]], 1);
}

__global__ __launch_bounds__(256) void scan1_k(const int* __restrict__ cnt,
                                               int* __restrict__ bsum, int M) {
    int i = blockIdx.x * 256 + threadIdx.x;
    int v = (i < M) ? cnt[i] : 0;
    __shared__ int l[256];
    l[threadIdx.x] = v;
    __syncthreads();
    for (int s = 128; s > 0; s >>= 1) {
        if (threadIdx.x < s) l[threadIdx.x] += l[threadIdx.x + s];
        __syncthreads();
    }
    if (threadIdx.x == 0) bsum[blockIdx.x] = l[0];
}

__global__ __launch_bounds__(256) void scan2_k(int* __restrict__ bsum, int NB) {
    int tid = threadIdx.x;
    int v = (tid < NB) ? bsum[tid] : 0;
    __shared__ int l[256];
    l[tid] = v;
    __syncthreads();
    for (int off = 1; off < 256; off <<= 1) {
        int t = (tid >= off) ? l[tid - off] : 0;
        __syncthreads();
        l[tid] += t;
        __syncthreads();
    }
    if (tid < NB) bsum[tid] = l[tid] - v;   // exclusive
}

__global__ __launch_bounds__(256) void scan3_k(const int* __restrict__ cnt,
                                               const int* __restrict__ bsum,
                                               int* __restrict__ offs,
                                               int* __restrict__ cur, int M) {
    int i = blockIdx.x * 256 + threadIdx.x;
    int tid = threadIdx.x;
    int v = (i < M) ? cnt[i] : 0;
    __shared__ int l[256];
    l[tid] = v;
    __syncthreads();
    for (int off = 1; off < 256; off <<= 1) {
        int t = (tid >= off) ? l[tid - off] : 0;
        __syncthreads();
        l[tid] += t;
        __syncthreads();
    }
    int excl = l[tid] - v + bsum[blockIdx.x];
    if (i < M) { offs[i] = excl; cur[i] = excl; }
    if (i == M - 1) offs[M] = excl + v;
}

// dst goes straight into epak[p].x (the .y weight slot is filled per-layer by ee_k)
__global__ void fill_csr_k(const int* __restrict__ src, const int* __restrict__ dst,
                           int* __restrict__ cur, int2* __restrict__ epak, int E) {
    int e = blockIdx.x * blockDim.x + threadIdx.x;
    if (e < E) {
        int p = atomicAdd(&cur[src[e]], 1);
        epak[p].x = dst[e];
    }
}

// ---------------------------------------------------------------- GEMM + BN-in + attention dots
// H = (X*scale+shift) @ W ; es = H@a[:128] ; ed = H@a[128:] ; H stored bf16.
__global__ __launch_bounds__(256) void gemm_bn_dots_k(const float* __restrict__ X,
                                                      const float* __restrict__ W,
                                                      const float* __restrict__ scale,
                                                      const float* __restrict__ shift,
                                                      const float* __restrict__ avec,
                                                      __hip_bfloat16* __restrict__ Hb,
                                                      float* __restrict__ es,
                                                      float* __restrict__ ed, int M) {
    __shared__ float As[16][132];
    __shared__ float Bs[16][128];
    __shared__ float sc[128], sh[128], sa_s[128], sa_d[128];
    int tid = threadIdx.x;
    if (tid < 128) {
        sc[tid] = scale[tid]; sh[tid] = shift[tid];
        sa_s[tid] = avec[tid]; sa_d[tid] = avec[128 + tid];
    }
    __syncthreads();
    int row0 = blockIdx.x * 128;
    int tc = tid & 15, tr = tid >> 4;
    float acc[8][8];
#pragma unroll
    for (int i = 0; i < 8; i++)
#pragma unroll
        for (int j = 0; j < 8; j++) acc[i][j] = 0.f;

    for (int k0 = 0; k0 < 128; k0 += 16) {
        int r = tid >> 2;
        int kk = (tid & 3) * 4;
#pragma unroll
        for (int half = 0; half < 2; half++) {
            int rr = r + half * 64;
            int grow = row0 + rr;
            float4 v = make_float4(0.f, 0.f, 0.f, 0.f);
            if (grow < M) v = *(const float4*)&X[(size_t)grow * FD + k0 + kk];
            v.x = v.x * sc[k0 + kk]     + sh[k0 + kk];
            v.y = v.y * sc[k0 + kk + 1] + sh[k0 + kk + 1];
            v.z = v.z * sc[k0 + kk + 2] + sh[k0 + kk + 2];
            v.w = v.w * sc[k0 + kk + 3] + sh[k0 + kk + 3];
            As[kk][rr] = v.x; As[kk + 1][rr] = v.y; As[kk + 2][rr] = v.z; As[kk + 3][rr] = v.w;
        }
        int kb = tid >> 5;
        int cb = (tid & 31) * 4;
#pragma unroll
        for (int half = 0; half < 2; half++) {
            int kr = kb + half * 8;
            *(float4*)&Bs[kr][cb] = *(const float4*)&W[(size_t)(k0 + kr) * FD + cb];
        }
        __syncthreads();
#pragma unroll
        for (int k = 0; k < 16; k++) {
            float a[8], b[8];
#pragma unroll
            for (int i = 0; i < 8; i++) a[i] = As[k][tr * 8 + i];
#pragma unroll
            for (int j = 0; j < 8; j++) b[j] = Bs[k][tc * 8 + j];
#pragma unroll
            for (int i = 0; i < 8; i++)
#pragma unroll
                for (int j = 0; j < 8; j++) acc[i][j] += a[i] * b[j];
        }
        __syncthreads();
    }

    // Epilogue: attention dots (16-lane butterfly over tc) + bf16 store of H.
#pragma unroll
    for (int i = 0; i < 8; i++) {
        int grow = row0 + tr * 8 + i;
        float ps = 0.f, pd = 0.f;
#pragma unroll
        for (int j = 0; j < 8; j++) {
            ps += acc[i][j] * sa_s[tc * 8 + j];
            pd += acc[i][j] * sa_d[tc * 8 + j];
        }
#pragma unroll
        for (int o = 8; o > 0; o >>= 1) { ps += __shfl_xor(ps, o); pd += __shfl_xor(pd, o); }
        if (grow < M) {
            if (tc == 0) { es[grow] = ps; ed[grow] = pd; }
            union { uint4 q; __hip_bfloat16 h[8]; } p;
#pragma unroll
            for (int j = 0; j < 8; j++) p.h[j] = __float2bfloat16(acc[i][j]);
            *(uint4*)&Hb[(size_t)grow * FD + tc * 8] = p.q;
        }
    }
}

// ---------------------------------------------------------------- per-edge ee + rowsum (wave per node)
// fills epak[e].y with ee weight; also writes rowsum[node].
__global__ __launch_bounds__(256) void ee_k(const float* __restrict__ es_,
                                            const float* __restrict__ ed_,
                                            const int* __restrict__ offs,
                                            int2* __restrict__ epak,
                                            float* __restrict__ rowsum, int M) {
    int wave = (blockIdx.x * blockDim.x + threadIdx.x) >> 6;
    int lane = threadIdx.x & 63;
    if (wave >= M) return;
    int s0 = offs[wave], s1 = offs[wave + 1];
    float es = es_[wave];
    float rs = 0.f;
    for (int base = s0; base < s1; base += 64) {
        int m = s1 - base; if (m > 64) m = 64;
        if (lane < m) {
            int d = epak[base + lane].x;
            float e = es + ed_[d];
            float lr = e > 0.f ? e : 0.2f * e;
            float v = __expf(-lr);
            epak[base + lane].y = __float_as_int(v);
            rs += v;
        }
    }
#pragma unroll
    for (int o = 32; o > 0; o >>= 1) rs += __shfl_xor(rs, o);
    if (lane == 0) rowsum[wave] = rs;
}

// ---------------------------------------------------------------- aggregation (wave per node, scalar-pipe edge stream)
__global__ __launch_bounds__(256) void agg_k(const __hip_bfloat16* __restrict__ Hb,
                                             const float* __restrict__ rowsum,
                                             const int* __restrict__ offs,
                                             const int2* __restrict__ epak,
                                             float* __restrict__ Out, int M) {
    // node is wave-uniform: force it into an SGPR so epak[e]/offs[] become s_loads.
    int node = __builtin_amdgcn_readfirstlane((int)((blockIdx.x * blockDim.x + threadIdx.x) >> 6));
    int lane = threadIdx.x & 63;
    if (node >= M) return;
    int s0 = offs[node], s1 = offs[node + 1];
    const unsigned int* Hrow = (const unsigned int*)Hb;   // one dword = bf16x2 per lane
    float2 a0 = make_float2(0.f, 0.f), a1 = make_float2(0.f, 0.f);
    int e = s0;
    for (; e + 4 <= s1; e += 4) {
        int2 p0 = epak[e];
        int2 p1 = epak[e + 1];
        int2 p2 = epak[e + 2];
        int2 p3 = epak[e + 3];
        unsigned int r0 = Hrow[(size_t)p0.x * 64 + lane];
        unsigned int r1 = Hrow[(size_t)p1.x * 64 + lane];
        unsigned int r2 = Hrow[(size_t)p2.x * 64 + lane];
        unsigned int r3 = Hrow[(size_t)p3.x * 64 + lane];
        float w0 = __int_as_float(p0.y), w1 = __int_as_float(p1.y);
        float w2 = __int_as_float(p2.y), w3 = __int_as_float(p3.y);
        a0.x += w0 * __int_as_float(r0 << 16);
        a0.y += w0 * __int_as_float(r0 & 0xffff0000u);
        a1.x += w1 * __int_as_float(r1 << 16);
        a1.y += w1 * __int_as_float(r1 & 0xffff0000u);
        a0.x += w2 * __int_as_float(r2 << 16);
        a0.y += w2 * __int_as_float(r2 & 0xffff0000u);
        a1.x += w3 * __int_as_float(r3 << 16);
        a1.y += w3 * __int_as_float(r3 & 0xffff0000u);
    }
    for (; e < s1; e++) {
        int2 p = epak[e];
        unsigned int r = Hrow[(size_t)p.x * 64 + lane];
        float w = __int_as_float(p.y);
        a0.x += w * __int_as_float(r << 16);
        a0.y += w * __int_as_float(r & 0xffff0000u);
    }
    float inv = 1.f / (rowsum[node] + 1e-16f);
    float vx = (a0.x + a1.x) * inv;
    float vy = (a0.y + a1.y) * inv;
    vx = vx > 0.f ? vx : (__expf(vx) - 1.f);   // elu, alpha=1
    vy = vy > 0.f ? vy : (__expf(vy) - 1.f);
    ((float2*)Out)[(size_t)node * 64 + lane] = make_float2(vx, vy);
}

// ---------------------------------------------------------------- BN stats / finalize
__global__ void bnstats_k(const float* __restrict__ X, float* __restrict__ sums,
                          float* __restrict__ sumsq, int M) {
    int f = threadIdx.x & 127;
    int half = threadIdx.x >> 7;
    float s1 = 0.f, s2 = 0.f;
    for (int r = blockIdx.x * 2 + half; r < M; r += gridDim.x * 2) {
        float v = X[(size_t)r * FD + f];
        s1 += v; s2 += v * v;
    }
    __shared__ float l1[256], l2[256];
    l1[threadIdx.x] = s1; l2[threadIdx.x] = s2;
    __syncthreads();
    if (half == 0) {
        atomicAdd(&sums[f], l1[f] + l1[f + 128]);
        atomicAdd(&sumsq[f], l2[f] + l2[f + 128]);
    }
}

__global__ void init_affine_k(float* scale, float* shift, float* sums, float* sumsq) {
    int f = threadIdx.x;
    scale[f] = 1.f; shift[f] = 0.f; sums[f] = 0.f; sumsq[f] = 0.f;
}

__global__ void bnfinal_k(float* sums, float* sumsq, const float* __restrict__ g,
                          const float* __restrict__ b, float* scale, float* shift, float invN) {
    int f = threadIdx.x;
    float mu = sums[f] * invN;
    float var = sumsq[f] * invN - mu * mu;
    float sc = g[f] * rsqrtf(var + 1e-5f);
    scale[f] = sc;
    shift[f] = b[f] - mu * sc;
    sums[f] = 0.f; sumsq[f] = 0.f;   // ready for next stats pass
}

// ---------------------------------------------------------------- pooling (sorted graph ids)
__global__ void pool_k(const float* __restrict__ X, const int* __restrict__ gi,
                       float* __restrict__ pooled, int M) {
    int f = threadIdx.x & 127;
    int half = threadIdx.x >> 7;
    int r0 = blockIdx.x * 128 + half;
    int rend = min(blockIdx.x * 128 + 128, M);
    int curg = -1; float acc = 0.f;
    for (int r = r0; r < rend; r += 2) {
        int g = gi[r];
        if (g != curg) {
            if (curg >= 0) atomicAdd(&pooled[(size_t)curg * FD + f], acc);
            curg = g; acc = 0.f;
        }
        acc += X[(size_t)r * FD + f];
    }
    if (curg >= 0) atomicAdd(&pooled[(size_t)curg * FD + f], acc);
}

// ---------------------------------------------------------------- small MLP
__global__ void fc_relu_k(const float* __restrict__ X, const float* __restrict__ Wt,
                          const float* __restrict__ b, float* __restrict__ Y,
                          int K, int Ncols) {
    int g = blockIdx.x;
    int j = threadIdx.x;
    extern __shared__ float xrow[];
    for (int k = threadIdx.x; k < K; k += blockDim.x) xrow[k] = X[(size_t)g * K + k];
    __syncthreads();
    float s = b[j];
    for (int k = 0; k < K; k++) s += xrow[k] * Wt[(size_t)k * Ncols + j];
    Y[(size_t)g * Ncols + j] = fmaxf(s, 0.f);
}

__global__ void fc3_k(const float* __restrict__ X, const float* __restrict__ W,
                      const float* __restrict__ b, float* __restrict__ out) {
    int g = blockIdx.x;
    int l = threadIdx.x;
    float2 x2 = ((const float2*)X)[g * 64 + l];
    float s0 = x2.x * W[(2 * l) * 2]     + x2.y * W[(2 * l + 1) * 2];
    float s1 = x2.x * W[(2 * l) * 2 + 1] + x2.y * W[(2 * l + 1) * 2 + 1];
#pragma unroll
    for (int o = 32; o > 0; o >>= 1) { s0 += __shfl_xor(s0, o); s1 += __shfl_xor(s1, o); }
    if (l == 0) { out[g * 2] = s0 + b[0]; out[g * 2 + 1] = s1 + b[1]; }
}

// ---------------------------------------------------------------- launcher
extern "C" void kernel_launch(void* const* d_in, const int* in_sizes, int n_in,
                              void* d_out, int out_size, void* d_ws, size_t ws_size,
                              hipStream_t stream) {
    const int*   adj  = (const int*)d_in[0];
    const float* xin  = (const float*)d_in[1];
    const int*   gi   = (const int*)d_in[2];
    const float* W1   = (const float*)d_in[4];
    const float* a1   = (const float*)d_in[5];
    const float* bn2g = (const float*)d_in[6];
    const float* bn2b = (const float*)d_in[7];
    const float* W2   = (const float*)d_in[8];
    const float* a2   = (const float*)d_in[9];
    const float* bn3g = (const float*)d_in[10];
    const float* bn3b = (const float*)d_in[11];
    const float* W3   = (const float*)d_in[12];
    const float* a3   = (const float*)d_in[13];
    const float* fc1w = (const float*)d_in[14];
    const float* fc1b = (const float*)d_in[15];
    const float* fc2w = (const float*)d_in[16];
    const float* fc2b = (const float*)d_in[17];
    const float* fc3w = (const float*)d_in[18];
    const float* fc3b = (const float*)d_in[19];
    float* out = (float*)d_out;

    const int N = N_NODES, E = N_EDGES, G = N_GRAPHS;

    float* buf1   = (float*)d_ws;                 // [N,128] fp32 (agg out / gemm in)
    __hip_bfloat16* Hb = (__hip_bfloat16*)(buf1 + (size_t)N * FD);  // [N,128] bf16
    float* es     = (float*)(Hb + (size_t)N * FD); // [N]
    float* ed     = es + N;                       // [N]
    float* rowsum = ed + N;                       // [N]
    float* scale  = rowsum + N;                   // [128]
    float* shift  = scale + FD;                   // [128]
    float* sums   = shift + FD;                   // [128]
    float* sumsq  = sums + FD;                    // [128]
    float* pooled = sumsq + FD;                   // [G,128]
    float* t1     = pooled + (size_t)G * FD;      // [G,256]
    float* t2     = t1 + (size_t)G * 256;         // [G,128]
    int*   degcnt = (int*)(t2 + (size_t)G * FD);  // [N]
    int*   offs   = degcnt + N;                   // [N+1]
    int*   cur    = offs + (N + 1);               // [N]
    int*   bsum   = cur + N;                      // [256]
    int2*  epak   = (int2*)(bsum + 256);          // [E] (dst, ee-weight)

    const int* srcp = adj;
    const int* dstp = adj + E;

    const int NB = (N + 255) / 256;

    // ---- CSR build (once; reused by all 3 layers)
    hipMemsetAsync(degcnt, 0, (size_t)N * sizeof(int), stream);
    count_deg_k<<<(E + 255) / 256, 256, 0, stream>>>(srcp, degcnt, E);
    scan1_k<<<NB, 256, 0, stream>>>(degcnt, bsum, N);
    scan2_k<<<1, 256, 0, stream>>>(bsum, NB);
    scan3_k<<<NB, 256, 0, stream>>>(degcnt, bsum, offs, cur, N);
    fill_csr_k<<<(E + 255) / 256, 256, 0, stream>>>(srcp, dstp, cur, epak, E);
    init_affine_k<<<1, 128, 0, stream>>>(scale, shift, sums, sumsq);

    const int gemm_grid = (N + 127) / 128;
    const int wave_grid = (N + 3) / 4;      // 4 waves per 256-thread block
    const float invN = 1.0f / (float)N;

    // ---- layer 1
    gemm_bn_dots_k<<<gemm_grid, 256, 0, stream>>>(xin, W1, scale, shift, a1, Hb, es, ed, N);
    ee_k<<<wave_grid, 256, 0, stream>>>(es, ed, offs, epak, rowsum, N);
    agg_k<<<wave_grid, 256, 0, stream>>>(Hb, rowsum, offs, epak, buf1, N);
    bnstats_k<<<256, 256, 0, stream>>>(buf1, sums, sumsq, N);
    bnfinal_k<<<1, 128, 0, stream>>>(sums, sumsq, bn2g, bn2b, scale, shift, invN);

    // ---- layer 2 (BN fused into GEMM A-load)
    gemm_bn_dots_k<<<gemm_grid, 256, 0, stream>>>(buf1, W2, scale, shift, a2, Hb, es, ed, N);
    ee_k<<<wave_grid, 256, 0, stream>>>(es, ed, offs, epak, rowsum, N);
    agg_k<<<wave_grid, 256, 0, stream>>>(Hb, rowsum, offs, epak, buf1, N);
    bnstats_k<<<256, 256, 0, stream>>>(buf1, sums, sumsq, N);
    bnfinal_k<<<1, 128, 0, stream>>>(sums, sumsq, bn3g, bn3b, scale, shift, invN);

    // ---- layer 3
    gemm_bn_dots_k<<<gemm_grid, 256, 0, stream>>>(buf1, W3, scale, shift, a3, Hb, es, ed, N);
    ee_k<<<wave_grid, 256, 0, stream>>>(es, ed, offs, epak, rowsum, N);
    agg_k<<<wave_grid, 256, 0, stream>>>(Hb, rowsum, offs, epak, buf1, N);

    // ---- pooling + MLP
    hipMemsetAsync(pooled, 0, (size_t)G * FD * sizeof(float), stream);
    pool_k<<<(N + 127) / 128, 256, 0, stream>>>(buf1, gi, pooled, N);
    fc_relu_k<<<G, 256, FD * sizeof(float), stream>>>(pooled, fc1w, fc1b, t1, FD, 256);
    fc_relu_k<<<G, 128, 256 * sizeof(float), stream>>>(t1, fc2w, fc2b, t2, 256, FD);
    fc3_k<<<G, 64, 0, stream>>>(t2, fc3w, fc3b, out);
}

// Round 6
// 532.546 us; speedup vs baseline: 1.2272x; 1.0336x over previous
//
#include <hip/hip_runtime.h>
#include <hip/hip_bf16.h>

#define N_NODES 50000
#define N_EDGES 800000
#define FD 128
#define N_GRAPHS 256
#define NPART 6250   // N_NODES / 8 (nodes per XCD partition)

// ---------------------------------------------------------------- CSR build (XCD-partitioned)
// blockIdx%8 selects a node partition; with round-robin block->XCD dispatch this keeps
// cnt/cur atomics and epak scatter-writes XCD-local so lines coalesce in that XCD's L2.
__global__ __launch_bounds__(256) void count_deg_part_k(const int* __restrict__ src,
                                                        int* __restrict__ cnt, int E) {
    int part = blockIdx.x & 7;
    int lo = part * NPART, hi = lo + NPART;
    int stride = (gridDim.x >> 3) * 256;
    for (int e = (blockIdx.x >> 3) * 256 + threadIdx.x; e < E; e += stride) {
        int s = src[e];
        if (s >= lo && s < hi) atomicAdd(&cnt[s], 1);
    }
}

__global__ __launch_bounds__(256) void fill_csr_part_k(const int* __restrict__ src,
                                                       const int* __restrict__ dst,
                                                       int* __restrict__ cur,
                                                       int2* __restrict__ epak, int E) {
    int part = blockIdx.x & 7;
    int lo = part * NPART, hi = lo + NPART;
    int stride = (gridDim.x >> 3) * 256;
    for (int e = (blockIdx.x >> 3) * 256 + threadIdx.x; e < E; e += stride) {
        int s = src[e];
        if (s >= lo && s < hi) {
            int p = atomicAdd(&cur[s], 1);
            epak[p].x = dst[e];
        }
    }
}

__global__ __launch_bounds__(256) void scan1_k(const int* __restrict__ cnt,
                                               int* __restrict__ bsum, int M) {
    int i = blockIdx.x * 256 + threadIdx.x;
    int v = (i < M) ? cnt[i] : 0;
    __shared__ int l[256];
    l[threadIdx.x] = v;
    __syncthreads();
    for (int s = 128; s > 0; s >>= 1) {
        if (threadIdx.x < s) l[threadIdx.x] += l[threadIdx.x + s];
        __syncthreads();
    }
    if (threadIdx.x == 0) bsum[blockIdx.x] = l[0];
}

__global__ __launch_bounds__(256) void scan2_k(int* __restrict__ bsum, int NB) {
    int tid = threadIdx.x;
    int v = (tid < NB) ? bsum[tid] : 0;
    __shared__ int l[256];
    l[tid] = v;
    __syncthreads();
    for (int off = 1; off < 256; off <<= 1) {
        int t = (tid >= off) ? l[tid - off] : 0;
        __syncthreads();
        l[tid] += t;
        __syncthreads();
    }
    if (tid < NB) bsum[tid] = l[tid] - v;   // exclusive
}

__global__ __launch_bounds__(256) void scan3_k(const int* __restrict__ cnt,
                                               const int* __restrict__ bsum,
                                               int* __restrict__ offs,
                                               int* __restrict__ cur, int M) {
    int i = blockIdx.x * 256 + threadIdx.x;
    int tid = threadIdx.x;
    int v = (i < M) ? cnt[i] : 0;
    __shared__ int l[256];
    l[tid] = v;
    __syncthreads();
    for (int off = 1; off < 256; off <<= 1) {
        int t = (tid >= off) ? l[tid - off] : 0;
        __syncthreads();
        l[tid] += t;
        __syncthreads();
    }
    int excl = l[tid] - v + bsum[blockIdx.x];
    if (i < M) { offs[i] = excl; cur[i] = excl; }
    if (i == M - 1) offs[M] = excl + v;
}

// ---------------------------------------------------------------- GEMM + BN-in + attention dots
// H = (X*scale+shift) @ W ; es = H@a[:128] ; ed = H@a[128:] ; H stored bf16.
__global__ __launch_bounds__(256) void gemm_bn_dots_k(const float* __restrict__ X,
                                                      const float* __restrict__ W,
                                                      const float* __restrict__ scale,
                                                      const float* __restrict__ shift,
                                                      const float* __restrict__ avec,
                                                      __hip_bfloat16* __restrict__ Hb,
                                                      float* __restrict__ es,
                                                      float* __restrict__ ed, int M) {
    __shared__ float As[16][132];
    __shared__ float Bs[16][128];
    __shared__ float sc[128], sh[128], sa_s[128], sa_d[128];
    int tid = threadIdx.x;
    if (tid < 128) {
        sc[tid] = scale[tid]; sh[tid] = shift[tid];
        sa_s[tid] = avec[tid]; sa_d[tid] = avec[128 + tid];
    }
    __syncthreads();
    int row0 = blockIdx.x * 128;
    int tc = tid & 15, tr = tid >> 4;
    float acc[8][8];
#pragma unroll
    for (int i = 0; i < 8; i++)
#pragma unroll
        for (int j = 0; j < 8; j++) acc[i][j] = 0.f;

    for (int k0 = 0; k0 < 128; k0 += 16) {
        int r = tid >> 2;
        int kk = (tid & 3) * 4;
#pragma unroll
        for (int half = 0; half < 2; half++) {
            int rr = r + half * 64;
            int grow = row0 + rr;
            float4 v = make_float4(0.f, 0.f, 0.f, 0.f);
            if (grow < M) v = *(const float4*)&X[(size_t)grow * FD + k0 + kk];
            v.x = v.x * sc[k0 + kk]     + sh[k0 + kk];
            v.y = v.y * sc[k0 + kk + 1] + sh[k0 + kk + 1];
            v.z = v.z * sc[k0 + kk + 2] + sh[k0 + kk + 2];
            v.w = v.w * sc[k0 + kk + 3] + sh[k0 + kk + 3];
            As[kk][rr] = v.x; As[kk + 1][rr] = v.y; As[kk + 2][rr] = v.z; As[kk + 3][rr] = v.w;
        }
        int kb = tid >> 5;
        int cb = (tid & 31) * 4;
#pragma unroll
        for (int half = 0; half < 2; half++) {
            int kr = kb + half * 8;
            *(float4*)&Bs[kr][cb] = *(const float4*)&W[(size_t)(k0 + kr) * FD + cb];
        }
        __syncthreads();
#pragma unroll
        for (int k = 0; k < 16; k++) {
            float a[8], b[8];
#pragma unroll
            for (int i = 0; i < 8; i++) a[i] = As[k][tr * 8 + i];
#pragma unroll
            for (int j = 0; j < 8; j++) b[j] = Bs[k][tc * 8 + j];
#pragma unroll
            for (int i = 0; i < 8; i++)
#pragma unroll
                for (int j = 0; j < 8; j++) acc[i][j] += a[i] * b[j];
        }
        __syncthreads();
    }

    // Epilogue: attention dots (16-lane butterfly over tc) + bf16 store of H.
#pragma unroll
    for (int i = 0; i < 8; i++) {
        int grow = row0 + tr * 8 + i;
        float ps = 0.f, pd = 0.f;
#pragma unroll
        for (int j = 0; j < 8; j++) {
            ps += acc[i][j] * sa_s[tc * 8 + j];
            pd += acc[i][j] * sa_d[tc * 8 + j];
        }
#pragma unroll
        for (int o = 8; o > 0; o >>= 1) { ps += __shfl_xor(ps, o); pd += __shfl_xor(pd, o); }
        if (grow < M) {
            if (tc == 0) { es[grow] = ps; ed[grow] = pd; }
            union { uint4 q; __hip_bfloat16 h[8]; } p;
#pragma unroll
            for (int j = 0; j < 8; j++) p.h[j] = __float2bfloat16(acc[i][j]);
            *(uint4*)&Hb[(size_t)grow * FD + tc * 8] = p.q;
        }
    }
}

// ---------------------------------------------------------------- per-edge ee + rowsum (wave per node)
// fills epak[e].y with ee weight; also writes rowsum[node].
__global__ __launch_bounds__(256) void ee_k(const float* __restrict__ es_,
                                            const float* __restrict__ ed_,
                                            const int* __restrict__ offs,
                                            int2* __restrict__ epak,
                                            float* __restrict__ rowsum, int M) {
    int wave = (blockIdx.x * blockDim.x + threadIdx.x) >> 6;
    int lane = threadIdx.x & 63;
    if (wave >= M) return;
    int s0 = offs[wave], s1 = offs[wave + 1];
    float es = es_[wave];
    float rs = 0.f;
    for (int base = s0; base < s1; base += 64) {
        int m = s1 - base; if (m > 64) m = 64;
        if (lane < m) {
            int d = epak[base + lane].x;
            float e = es + ed_[d];
            float lr = e > 0.f ? e : 0.2f * e;
            float v = __expf(-lr);
            epak[base + lane].y = __float_as_int(v);
            rs += v;
        }
    }
#pragma unroll
    for (int o = 32; o > 0; o >>= 1) rs += __shfl_xor(rs, o);
    if (lane == 0) rowsum[wave] = rs;
}

// ---------------------------------------------------------------- aggregation (wave per node, scalar-pipe edge stream)
__global__ __launch_bounds__(256) void agg_k(const __hip_bfloat16* __restrict__ Hb,
                                             const float* __restrict__ rowsum,
                                             const int* __restrict__ offs,
                                             const int2* __restrict__ epak,
                                             float* __restrict__ Out, int M) {
    // node is wave-uniform: force it into an SGPR so epak[e]/offs[] become s_loads.
    int node = __builtin_amdgcn_readfirstlane((int)((blockIdx.x * blockDim.x + threadIdx.x) >> 6));
    int lane = threadIdx.x & 63;
    if (node >= M) return;
    int s0 = offs[node], s1 = offs[node + 1];
    const unsigned int* Hrow = (const unsigned int*)Hb;   // one dword = bf16x2 per lane
    float2 a0 = make_float2(0.f, 0.f), a1 = make_float2(0.f, 0.f);
    int e = s0;
    for (; e + 4 <= s1; e += 4) {
        int2 p0 = epak[e];
        int2 p1 = epak[e + 1];
        int2 p2 = epak[e + 2];
        int2 p3 = epak[e + 3];
        unsigned int r0 = Hrow[(size_t)p0.x * 64 + lane];
        unsigned int r1 = Hrow[(size_t)p1.x * 64 + lane];
        unsigned int r2 = Hrow[(size_t)p2.x * 64 + lane];
        unsigned int r3 = Hrow[(size_t)p3.x * 64 + lane];
        float w0 = __int_as_float(p0.y), w1 = __int_as_float(p1.y);
        float w2 = __int_as_float(p2.y), w3 = __int_as_float(p3.y);
        a0.x += w0 * __int_as_float(r0 << 16);
        a0.y += w0 * __int_as_float(r0 & 0xffff0000u);
        a1.x += w1 * __int_as_float(r1 << 16);
        a1.y += w1 * __int_as_float(r1 & 0xffff0000u);
        a0.x += w2 * __int_as_float(r2 << 16);
        a0.y += w2 * __int_as_float(r2 & 0xffff0000u);
        a1.x += w3 * __int_as_float(r3 << 16);
        a1.y += w3 * __int_as_float(r3 & 0xffff0000u);
    }
    for (; e < s1; e++) {
        int2 p = epak[e];
        unsigned int r = Hrow[(size_t)p.x * 64 + lane];
        float w = __int_as_float(p.y);
        a0.x += w * __int_as_float(r << 16);
        a0.y += w * __int_as_float(r & 0xffff0000u);
    }
    float inv = 1.f / (rowsum[node] + 1e-16f);
    float vx = (a0.x + a1.x) * inv;
    float vy = (a0.y + a1.y) * inv;
    vx = vx > 0.f ? vx : (__expf(vx) - 1.f);   // elu, alpha=1
    vy = vy > 0.f ? vy : (__expf(vy) - 1.f);
    ((float2*)Out)[(size_t)node * 64 + lane] = make_float2(vx, vy);
}

// ---------------------------------------------------------------- BN stats / finalize
__global__ void bnstats_k(const float* __restrict__ X, float* __restrict__ sums,
                          float* __restrict__ sumsq, int M) {
    int f = threadIdx.x & 127;
    int half = threadIdx.x >> 7;
    float s1 = 0.f, s2 = 0.f;
    for (int r = blockIdx.x * 2 + half; r < M; r += gridDim.x * 2) {
        float v = X[(size_t)r * FD + f];
        s1 += v; s2 += v * v;
    }
    __shared__ float l1[256], l2[256];
    l1[threadIdx.x] = s1; l2[threadIdx.x] = s2;
    __syncthreads();
    if (half == 0) {
        atomicAdd(&sums[f], l1[f] + l1[f + 128]);
        atomicAdd(&sumsq[f], l2[f] + l2[f + 128]);
    }
}

__global__ void init_affine_k(float* scale, float* shift, float* sums, float* sumsq) {
    int f = threadIdx.x;
    scale[f] = 1.f; shift[f] = 0.f; sums[f] = 0.f; sumsq[f] = 0.f;
}

__global__ void bnfinal_k(float* sums, float* sumsq, const float* __restrict__ g,
                          const float* __restrict__ b, float* scale, float* shift, float invN) {
    int f = threadIdx.x;
    float mu = sums[f] * invN;
    float var = sumsq[f] * invN - mu * mu;
    float sc = g[f] * rsqrtf(var + 1e-5f);
    scale[f] = sc;
    shift[f] = b[f] - mu * sc;
    sums[f] = 0.f; sumsq[f] = 0.f;   // ready for next stats pass
}

// ---------------------------------------------------------------- pooling (sorted graph ids)
__global__ void pool_k(const float* __restrict__ X, const int* __restrict__ gi,
                       float* __restrict__ pooled, int M) {
    int f = threadIdx.x & 127;
    int half = threadIdx.x >> 7;
    int r0 = blockIdx.x * 128 + half;
    int rend = min(blockIdx.x * 128 + 128, M);
    int curg = -1; float acc = 0.f;
    for (int r = r0; r < rend; r += 2) {
        int g = gi[r];
        if (g != curg) {
            if (curg >= 0) atomicAdd(&pooled[(size_t)curg * FD + f], acc);
            curg = g; acc = 0.f;
        }
        acc += X[(size_t)r * FD + f];
    }
    if (curg >= 0) atomicAdd(&pooled[(size_t)curg * FD + f], acc);
}

// ---------------------------------------------------------------- small MLP
__global__ void fc_relu_k(const float* __restrict__ X, const float* __restrict__ Wt,
                          const float* __restrict__ b, float* __restrict__ Y,
                          int K, int Ncols) {
    int g = blockIdx.x;
    int j = threadIdx.x;
    extern __shared__ float xrow[];
    for (int k = threadIdx.x; k < K; k += blockDim.x) xrow[k] = X[(size_t)g * K + k];
    __syncthreads();
    float s = b[j];
    for (int k = 0; k < K; k++) s += xrow[k] * Wt[(size_t)k * Ncols + j];
    Y[(size_t)g * Ncols + j] = fmaxf(s, 0.f);
}

__global__ void fc3_k(const float* __restrict__ X, const float* __restrict__ W,
                      const float* __restrict__ b, float* __restrict__ out) {
    int g = blockIdx.x;
    int l = threadIdx.x;
    float2 x2 = ((const float2*)X)[g * 64 + l];
    float s0 = x2.x * W[(2 * l) * 2]     + x2.y * W[(2 * l + 1) * 2];
    float s1 = x2.x * W[(2 * l) * 2 + 1] + x2.y * W[(2 * l + 1) * 2 + 1];
#pragma unroll
    for (int o = 32; o > 0; o >>= 1) { s0 += __shfl_xor(s0, o); s1 += __shfl_xor(s1, o); }
    if (l == 0) { out[g * 2] = s0 + b[0]; out[g * 2 + 1] = s1 + b[1]; }
}

// ---------------------------------------------------------------- launcher
extern "C" void kernel_launch(void* const* d_in, const int* in_sizes, int n_in,
                              void* d_out, int out_size, void* d_ws, size_t ws_size,
                              hipStream_t stream) {
    const int*   adj  = (const int*)d_in[0];
    const float* xin  = (const float*)d_in[1];
    const int*   gi   = (const int*)d_in[2];
    const float* W1   = (const float*)d_in[4];
    const float* a1   = (const float*)d_in[5];
    const float* bn2g = (const float*)d_in[6];
    const float* bn2b = (const float*)d_in[7];
    const float* W2   = (const float*)d_in[8];
    const float* a2   = (const float*)d_in[9];
    const float* bn3g = (const float*)d_in[10];
    const float* bn3b = (const float*)d_in[11];
    const float* W3   = (const float*)d_in[12];
    const float* a3   = (const float*)d_in[13];
    const float* fc1w = (const float*)d_in[14];
    const float* fc1b = (const float*)d_in[15];
    const float* fc2w = (const float*)d_in[16];
    const float* fc2b = (const float*)d_in[17];
    const float* fc3w = (const float*)d_in[18];
    const float* fc3b = (const float*)d_in[19];
    float* out = (float*)d_out;

    const int N = N_NODES, E = N_EDGES, G = N_GRAPHS;

    float* buf1   = (float*)d_ws;                 // [N,128] fp32 (agg out / gemm in)
    __hip_bfloat16* Hb = (__hip_bfloat16*)(buf1 + (size_t)N * FD);  // [N,128] bf16
    float* es     = (float*)(Hb + (size_t)N * FD); // [N]
    float* ed     = es + N;                       // [N]
    float* rowsum = ed + N;                       // [N]
    float* scale  = rowsum + N;                   // [128]
    float* shift  = scale + FD;                   // [128]
    float* sums   = shift + FD;                   // [128]
    float* sumsq  = sums + FD;                    // [128]
    float* pooled = sumsq + FD;                   // [G,128]
    float* t1     = pooled + (size_t)G * FD;      // [G,256]
    float* t2     = t1 + (size_t)G * 256;         // [G,128]
    int*   degcnt = (int*)(t2 + (size_t)G * FD);  // [N]
    int*   offs   = degcnt + N;                   // [N+1]
    int*   cur    = offs + (N + 1);               // [N]
    int*   bsum   = cur + N;                      // [256]
    int2*  epak   = (int2*)(bsum + 256);          // [E] (dst, ee-weight)

    const int* srcp = adj;
    const int* dstp = adj + E;

    const int NB = (N + 255) / 256;

    // ---- CSR build (once; reused by all 3 layers) — XCD-partitioned
    hipMemsetAsync(degcnt, 0, (size_t)N * sizeof(int), stream);
    count_deg_part_k<<<8 * 392, 256, 0, stream>>>(srcp, degcnt, E);
    scan1_k<<<NB, 256, 0, stream>>>(degcnt, bsum, N);
    scan2_k<<<1, 256, 0, stream>>>(bsum, NB);
    scan3_k<<<NB, 256, 0, stream>>>(degcnt, bsum, offs, cur, N);
    fill_csr_part_k<<<8 * 392, 256, 0, stream>>>(srcp, dstp, cur, epak, E);
    init_affine_k<<<1, 128, 0, stream>>>(scale, shift, sums, sumsq);

    const int gemm_grid = (N + 127) / 128;
    const int wave_grid = (N + 3) / 4;      // 4 waves per 256-thread block
    const float invN = 1.0f / (float)N;

    // ---- layer 1
    gemm_bn_dots_k<<<gemm_grid, 256, 0, stream>>>(xin, W1, scale, shift, a1, Hb, es, ed, N);
    ee_k<<<wave_grid, 256, 0, stream>>>(es, ed, offs, epak, rowsum, N);
    agg_k<<<wave_grid, 256, 0, stream>>>(Hb, rowsum, offs, epak, buf1, N);
    bnstats_k<<<256, 256, 0, stream>>>(buf1, sums, sumsq, N);
    bnfinal_k<<<1, 128, 0, stream>>>(sums, sumsq, bn2g, bn2b, scale, shift, invN);

    // ---- layer 2 (BN fused into GEMM A-load)
    gemm_bn_dots_k<<<gemm_grid, 256, 0, stream>>>(buf1, W2, scale, shift, a2, Hb, es, ed, N);
    ee_k<<<wave_grid, 256, 0, stream>>>(es, ed, offs, epak, rowsum, N);
    agg_k<<<wave_grid, 256, 0, stream>>>(Hb, rowsum, offs, epak, buf1, N);
    bnstats_k<<<256, 256, 0, stream>>>(buf1, sums, sumsq, N);
    bnfinal_k<<<1, 128, 0, stream>>>(sums, sumsq, bn3g, bn3b, scale, shift, invN);

    // ---- layer 3
    gemm_bn_dots_k<<<gemm_grid, 256, 0, stream>>>(buf1, W3, scale, shift, a3, Hb, es, ed, N);
    ee_k<<<wave_grid, 256, 0, stream>>>(es, ed, offs, epak, rowsum, N);
    agg_k<<<wave_grid, 256, 0, stream>>>(Hb, rowsum, offs, epak, buf1, N);

    // ---- pooling + MLP
    hipMemsetAsync(pooled, 0, (size_t)G * FD * sizeof(float), stream);
    pool_k<<<(N + 127) / 128, 256, 0, stream>>>(buf1, gi, pooled, N);
    fc_relu_k<<<G, 256, FD * sizeof(float), stream>>>(pooled, fc1w, fc1b, t1, FD, 256);
    fc_relu_k<<<G, 128, 256 * sizeof(float), stream>>>(t1, fc2w, fc2b, t2, 256, FD);
    fc3_k<<<G, 64, 0, stream>>>(t2, fc3w, fc3b, out);
}

// Round 7
// 494.192 us; speedup vs baseline: 1.3225x; 1.0776x over previous
//
#include <hip/hip_runtime.h>
#include <hip/hip_bf16.h>

#define N_NODES 50000
#define N_EDGES 800000
#define FD 128
#define N_GRAPHS 256
#define NPART 6250   // N_NODES / 8 (nodes per XCD partition)

typedef unsigned short u16;
typedef short bf16x8 __attribute__((ext_vector_type(8)));
typedef float f32x4 __attribute__((ext_vector_type(4)));

__device__ __forceinline__ u16 f2bf(float v) {
    __hip_bfloat16 h = __float2bfloat16(v);
    union { __hip_bfloat16 hh; u16 u; } c; c.hh = h; return c.u;
}
__device__ __forceinline__ float bf2f(u16 r) {
    return __uint_as_float(((unsigned int)r) << 16);
}

// ---------------------------------------------------------------- CSR build (XCD-partitioned)
__global__ __launch_bounds__(256) void count_deg_part_k(const int* __restrict__ src,
                                                        int* __restrict__ cnt, int E) {
    int part = blockIdx.x & 7;
    int lo = part * NPART, hi = lo + NPART;
    int stride = (gridDim.x >> 3) * 256;
    for (int e = (blockIdx.x >> 3) * 256 + threadIdx.x; e < E; e += stride) {
        int s = src[e];
        if (s >= lo && s < hi) atomicAdd(&cnt[s], 1);
    }
}

__global__ __launch_bounds__(256) void fill_csr_part_k(const int* __restrict__ src,
                                                       const int* __restrict__ dst,
                                                       int* __restrict__ cur,
                                                       int2* __restrict__ epak, int E) {
    int part = blockIdx.x & 7;
    int lo = part * NPART, hi = lo + NPART;
    int stride = (gridDim.x >> 3) * 256;
    for (int e = (blockIdx.x >> 3) * 256 + threadIdx.x; e < E; e += stride) {
        int s = src[e];
        if (s >= lo && s < hi) {
            int p = atomicAdd(&cur[s], 1);
            epak[p].x = dst[e];
        }
    }
}

__global__ __launch_bounds__(256) void scan1_k(const int* __restrict__ cnt,
                                               int* __restrict__ bsum, int M) {
    int i = blockIdx.x * 256 + threadIdx.x;
    int v = (i < M) ? cnt[i] : 0;
    __shared__ int l[256];
    l[threadIdx.x] = v;
    __syncthreads();
    for (int s = 128; s > 0; s >>= 1) {
        if (threadIdx.x < s) l[threadIdx.x] += l[threadIdx.x + s];
        __syncthreads();
    }
    if (threadIdx.x == 0) bsum[blockIdx.x] = l[0];
}

__global__ __launch_bounds__(256) void scan2_k(int* __restrict__ bsum, int NB) {
    int tid = threadIdx.x;
    int v = (tid < NB) ? bsum[tid] : 0;
    __shared__ int l[256];
    l[tid] = v;
    __syncthreads();
    for (int off = 1; off < 256; off <<= 1) {
        int t = (tid >= off) ? l[tid - off] : 0;
        __syncthreads();
        l[tid] += t;
        __syncthreads();
    }
    if (tid < NB) bsum[tid] = l[tid] - v;   // exclusive
}

__global__ __launch_bounds__(256) void scan3_k(const int* __restrict__ cnt,
                                               const int* __restrict__ bsum,
                                               int* __restrict__ offs,
                                               int* __restrict__ cur, int M) {
    int i = blockIdx.x * 256 + threadIdx.x;
    int tid = threadIdx.x;
    int v = (i < M) ? cnt[i] : 0;
    __shared__ int l[256];
    l[tid] = v;
    __syncthreads();
    for (int off = 1; off < 256; off <<= 1) {
        int t = (tid >= off) ? l[tid - off] : 0;
        __syncthreads();
        l[tid] += t;
        __syncthreads();
    }
    int excl = l[tid] - v + bsum[blockIdx.x];
    if (i < M) { offs[i] = excl; cur[i] = excl; }
    if (i == M - 1) offs[M] = excl + v;
}

// ---------------------------------------------------------------- input fp32 -> bf16
__global__ __launch_bounds__(256) void cvt_in_k(const float* __restrict__ X,
                                                u16* __restrict__ Xb, int n4) {
    int i = blockIdx.x * 256 + threadIdx.x;
    if (i < n4) {
        float4 v = ((const float4*)X)[i];
        ushort4 o;
        o.x = f2bf(v.x); o.y = f2bf(v.y); o.z = f2bf(v.z); o.w = f2bf(v.w);
        ((ushort4*)Xb)[i] = o;
    }
}

// ---------------------------------------------------------------- per-layer weight prep
// Wt[n][k] = bf16(scale[k]*W[k][n]);  cvec[n] = sum_k shift[k]*W[k][n]
__global__ __launch_bounds__(128) void wprep_k(const float* __restrict__ W,
                                               const float* __restrict__ scale,
                                               const float* __restrict__ shift,
                                               u16* __restrict__ Wt,
                                               float* __restrict__ cvec) {
    int n = blockIdx.x, k = threadIdx.x;
    float w = W[(size_t)k * FD + n];
    Wt[(size_t)n * FD + k] = f2bf(scale[k] * w);
    __shared__ float l[128];
    l[k] = shift[k] * w;
    __syncthreads();
    for (int s = 64; s > 0; s >>= 1) {
        if (k < s) l[k] += l[k + s];
        __syncthreads();
    }
    if (k == 0) cvec[n] = l[0];
}

// ---------------------------------------------------------------- MFMA GEMM + dots
// H[m][n] = sum_k Xb[m][k]*Wt[n][k] + cvec[n] ; es/ed = H @ a ; H stored bf16.
// BM=64 rows/block, 4 waves x (16 rows x 128 cols), mfma_f32_16x16x32_bf16.
__global__ __launch_bounds__(256) void gemm_mfma_k(const u16* __restrict__ Xb,
                                                   const u16* __restrict__ Wt,
                                                   const float* __restrict__ cvec,
                                                   const float* __restrict__ avec,
                                                   u16* __restrict__ Hb,
                                                   float* __restrict__ es,
                                                   float* __restrict__ ed, int M) {
    __shared__ u16 As[64][136];   // +8 pad: 2-way bank alias only
    __shared__ u16 Bs[128][136];
    __shared__ float sa_s[128], sa_d[128], cv[128];
    int tid = threadIdx.x;
    if (tid < 128) { sa_s[tid] = avec[tid]; sa_d[tid] = avec[128 + tid]; cv[tid] = cvec[tid]; }
    int row0 = blockIdx.x * 64;
    // stage B (Wt is [n][k] bf16, dense): thread t -> n=t>>1, k0=(t&1)*64
    {
        int n = tid >> 1, k0 = (tid & 1) * 64;
        const uint4* s = (const uint4*)(Wt + (size_t)n * FD + k0);
#pragma unroll
        for (int u = 0; u < 8; u++) *(uint4*)&Bs[n][k0 + u * 8] = s[u];
    }
    // stage A: thread t -> r=t>>2, k0=(t&3)*32
    {
        int r = tid >> 2, k0 = (tid & 3) * 32;
        int grow = row0 + r;
        if (grow < M) {
            const uint4* s = (const uint4*)(Xb + (size_t)grow * FD + k0);
#pragma unroll
            for (int u = 0; u < 4; u++) *(uint4*)&As[r][k0 + u * 8] = s[u];
        } else {
            uint4 z = make_uint4(0, 0, 0, 0);
#pragma unroll
            for (int u = 0; u < 4; u++) *(uint4*)&As[r][k0 + u * 8] = z;
        }
    }
    __syncthreads();

    int wave = tid >> 6, lane = tid & 63;
    int quad = lane >> 4, n16 = lane & 15;
    int rbase = wave * 16;
    f32x4 acc[8];
    f32x4 zz = {0.f, 0.f, 0.f, 0.f};
#pragma unroll
    for (int t = 0; t < 8; t++) acc[t] = zz;

#pragma unroll
    for (int kk = 0; kk < 128; kk += 32) {
        bf16x8 a = *(const bf16x8*)&As[rbase + n16][kk + quad * 8];
#pragma unroll
        for (int t = 0; t < 8; t++) {
            bf16x8 b = *(const bf16x8*)&Bs[t * 16 + n16][kk + quad * 8];
            acc[t] = __builtin_amdgcn_mfma_f32_16x16x32_bf16(a, b, acc[t], 0, 0, 0);
        }
    }

    // epilogue: +cvec, attention dots (butterfly over the 16 lanes of each quad), bf16 store
#pragma unroll
    for (int reg = 0; reg < 4; reg++) {
        int grow = row0 + rbase + quad * 4 + reg;
        float vals[8];
        float ps = 0.f, pd = 0.f;
#pragma unroll
        for (int t = 0; t < 8; t++) {
            float v = acc[t][reg] + cv[t * 16 + n16];
            vals[t] = v;
            ps += v * sa_s[t * 16 + n16];
            pd += v * sa_d[t * 16 + n16];
        }
#pragma unroll
        for (int o = 8; o > 0; o >>= 1) { ps += __shfl_xor(ps, o); pd += __shfl_xor(pd, o); }
        if (grow < M) {
            if (n16 == 0) { es[grow] = ps; ed[grow] = pd; }
#pragma unroll
            for (int t = 0; t < 8; t++)
                Hb[(size_t)grow * FD + t * 16 + n16] = f2bf(vals[t]);
        }
    }
}

// ---------------------------------------------------------------- per-edge ee + rowsum (wave per node)
__global__ __launch_bounds__(256) void ee_k(const float* __restrict__ es_,
                                            const float* __restrict__ ed_,
                                            const int* __restrict__ offs,
                                            int2* __restrict__ epak,
                                            float* __restrict__ rowsum, int M) {
    int wave = (blockIdx.x * blockDim.x + threadIdx.x) >> 6;
    int lane = threadIdx.x & 63;
    if (wave >= M) return;
    int s0 = offs[wave], s1 = offs[wave + 1];
    float es = es_[wave];
    float rs = 0.f;
    for (int base = s0; base < s1; base += 64) {
        int m = s1 - base; if (m > 64) m = 64;
        if (lane < m) {
            int d = epak[base + lane].x;
            float e = es + ed_[d];
            float lr = e > 0.f ? e : 0.2f * e;
            float v = __expf(-lr);
            epak[base + lane].y = __float_as_int(v);
            rs += v;
        }
    }
#pragma unroll
    for (int o = 32; o > 0; o >>= 1) rs += __shfl_xor(rs, o);
    if (lane == 0) rowsum[wave] = rs;
}

// ---------------------------------------------------------------- aggregation (wave per node, scalar-pipe edge stream)
__global__ __launch_bounds__(256) void agg_k(const u16* __restrict__ Hb,
                                             const float* __restrict__ rowsum,
                                             const int* __restrict__ offs,
                                             const int2* __restrict__ epak,
                                             u16* __restrict__ OutB,
                                             float* __restrict__ OutF,
                                             int fp32out, int M) {
    int node = __builtin_amdgcn_readfirstlane((int)((blockIdx.x * blockDim.x + threadIdx.x) >> 6));
    int lane = threadIdx.x & 63;
    if (node >= M) return;
    int s0 = offs[node], s1 = offs[node + 1];
    const unsigned int* Hrow = (const unsigned int*)Hb;   // one dword = bf16x2 per lane
    float2 a0 = make_float2(0.f, 0.f), a1 = make_float2(0.f, 0.f);
    int e = s0;
    for (; e + 4 <= s1; e += 4) {
        int2 p0 = epak[e];
        int2 p1 = epak[e + 1];
        int2 p2 = epak[e + 2];
        int2 p3 = epak[e + 3];
        unsigned int r0 = Hrow[(size_t)p0.x * 64 + lane];
        unsigned int r1 = Hrow[(size_t)p1.x * 64 + lane];
        unsigned int r2 = Hrow[(size_t)p2.x * 64 + lane];
        unsigned int r3 = Hrow[(size_t)p3.x * 64 + lane];
        float w0 = __int_as_float(p0.y), w1 = __int_as_float(p1.y);
        float w2 = __int_as_float(p2.y), w3 = __int_as_float(p3.y);
        a0.x += w0 * __int_as_float(r0 << 16);
        a0.y += w0 * __int_as_float(r0 & 0xffff0000u);
        a1.x += w1 * __int_as_float(r1 << 16);
        a1.y += w1 * __int_as_float(r1 & 0xffff0000u);
        a0.x += w2 * __int_as_float(r2 << 16);
        a0.y += w2 * __int_as_float(r2 & 0xffff0000u);
        a1.x += w3 * __int_as_float(r3 << 16);
        a1.y += w3 * __int_as_float(r3 & 0xffff0000u);
    }
    for (; e < s1; e++) {
        int2 p = epak[e];
        unsigned int r = Hrow[(size_t)p.x * 64 + lane];
        float w = __int_as_float(p.y);
        a0.x += w * __int_as_float(r << 16);
        a0.y += w * __int_as_float(r & 0xffff0000u);
    }
    float inv = 1.f / (rowsum[node] + 1e-16f);
    float vx = (a0.x + a1.x) * inv;
    float vy = (a0.y + a1.y) * inv;
    vx = vx > 0.f ? vx : (__expf(vx) - 1.f);   // elu, alpha=1
    vy = vy > 0.f ? vy : (__expf(vy) - 1.f);
    if (fp32out) {
        ((float2*)OutF)[(size_t)node * 64 + lane] = make_float2(vx, vy);
    } else {
        unsigned int pk = ((unsigned int)f2bf(vy) << 16) | f2bf(vx);
        ((unsigned int*)OutB)[(size_t)node * 64 + lane] = pk;
    }
}

// ---------------------------------------------------------------- BN stats (bf16 input) / finalize
__global__ void bnstats_b_k(const u16* __restrict__ Xb, float* __restrict__ sums,
                            float* __restrict__ sumsq, int M) {
    int f = threadIdx.x & 127;
    int half = threadIdx.x >> 7;
    float s1 = 0.f, s2 = 0.f;
    for (int r = blockIdx.x * 2 + half; r < M; r += gridDim.x * 2) {
        float v = bf2f(Xb[(size_t)r * FD + f]);
        s1 += v; s2 += v * v;
    }
    __shared__ float l1[256], l2[256];
    l1[threadIdx.x] = s1; l2[threadIdx.x] = s2;
    __syncthreads();
    if (half == 0) {
        atomicAdd(&sums[f], l1[f] + l1[f + 128]);
        atomicAdd(&sumsq[f], l2[f] + l2[f + 128]);
    }
}

__global__ void init_affine_k(float* scale, float* shift, float* sums, float* sumsq) {
    int f = threadIdx.x;
    scale[f] = 1.f; shift[f] = 0.f; sums[f] = 0.f; sumsq[f] = 0.f;
}

__global__ void bnfinal_k(float* sums, float* sumsq, const float* __restrict__ g,
                          const float* __restrict__ b, float* scale, float* shift, float invN) {
    int f = threadIdx.x;
    float mu = sums[f] * invN;
    float var = sumsq[f] * invN - mu * mu;
    float sc = g[f] * rsqrtf(var + 1e-5f);
    scale[f] = sc;
    shift[f] = b[f] - mu * sc;
    sums[f] = 0.f; sumsq[f] = 0.f;   // ready for next stats pass
}

// ---------------------------------------------------------------- pooling (sorted graph ids)
__global__ void pool_k(const float* __restrict__ X, const int* __restrict__ gi,
                       float* __restrict__ pooled, int M) {
    int f = threadIdx.x & 127;
    int half = threadIdx.x >> 7;
    int r0 = blockIdx.x * 128 + half;
    int rend = min(blockIdx.x * 128 + 128, M);
    int curg = -1; float acc = 0.f;
    for (int r = r0; r < rend; r += 2) {
        int g = gi[r];
        if (g != curg) {
            if (curg >= 0) atomicAdd(&pooled[(size_t)curg * FD + f], acc);
            curg = g; acc = 0.f;
        }
        acc += X[(size_t)r * FD + f];
    }
    if (curg >= 0) atomicAdd(&pooled[(size_t)curg * FD + f], acc);
}

// ---------------------------------------------------------------- small MLP
__global__ void fc_relu_k(const float* __restrict__ X, const float* __restrict__ Wt,
                          const float* __restrict__ b, float* __restrict__ Y,
                          int K, int Ncols) {
    int g = blockIdx.x;
    int j = threadIdx.x;
    extern __shared__ float xrow[];
    for (int k = threadIdx.x; k < K; k += blockDim.x) xrow[k] = X[(size_t)g * K + k];
    __syncthreads();
    float s = b[j];
    for (int k = 0; k < K; k++) s += xrow[k] * Wt[(size_t)k * Ncols + j];
    Y[(size_t)g * Ncols + j] = fmaxf(s, 0.f);
}

__global__ void fc3_k(const float* __restrict__ X, const float* __restrict__ W,
                      const float* __restrict__ b, float* __restrict__ out) {
    int g = blockIdx.x;
    int l = threadIdx.x;
    float2 x2 = ((const float2*)X)[g * 64 + l];
    float s0 = x2.x * W[(2 * l) * 2]     + x2.y * W[(2 * l + 1) * 2];
    float s1 = x2.x * W[(2 * l) * 2 + 1] + x2.y * W[(2 * l + 1) * 2 + 1];
#pragma unroll
    for (int o = 32; o > 0; o >>= 1) { s0 += __shfl_xor(s0, o); s1 += __shfl_xor(s1, o); }
    if (l == 0) { out[g * 2] = s0 + b[0]; out[g * 2 + 1] = s1 + b[1]; }
}

// ---------------------------------------------------------------- launcher
extern "C" void kernel_launch(void* const* d_in, const int* in_sizes, int n_in,
                              void* d_out, int out_size, void* d_ws, size_t ws_size,
                              hipStream_t stream) {
    const int*   adj  = (const int*)d_in[0];
    const float* xin  = (const float*)d_in[1];
    const int*   gi   = (const int*)d_in[2];
    const float* W1   = (const float*)d_in[4];
    const float* a1   = (const float*)d_in[5];
    const float* bn2g = (const float*)d_in[6];
    const float* bn2b = (const float*)d_in[7];
    const float* W2   = (const float*)d_in[8];
    const float* a2   = (const float*)d_in[9];
    const float* bn3g = (const float*)d_in[10];
    const float* bn3b = (const float*)d_in[11];
    const float* W3   = (const float*)d_in[12];
    const float* a3   = (const float*)d_in[13];
    const float* fc1w = (const float*)d_in[14];
    const float* fc1b = (const float*)d_in[15];
    const float* fc2w = (const float*)d_in[16];
    const float* fc2b = (const float*)d_in[17];
    const float* fc3w = (const float*)d_in[18];
    const float* fc3b = (const float*)d_in[19];
    float* out = (float*)d_out;

    const int N = N_NODES, E = N_EDGES, G = N_GRAPHS;

    float* buf1   = (float*)d_ws;                 // [N,128] fp32 (layer-3 agg out / pool in)
    u16*   Xb     = (u16*)(buf1 + (size_t)N * FD);   // [N,128] bf16 node features
    u16*   Hb     = Xb + (size_t)N * FD;             // [N,128] bf16 post-GEMM
    u16*   Wt     = Hb + (size_t)N * FD;             // [128,128] bf16 transposed, BN-folded
    float* es     = (float*)(Wt + FD * FD);       // [N]
    float* ed     = es + N;                       // [N]
    float* rowsum = ed + N;                       // [N]
    float* scale  = rowsum + N;                   // [128]
    float* shift  = scale + FD;                   // [128]
    float* sums   = shift + FD;                   // [128]
    float* sumsq  = sums + FD;                    // [128]
    float* cvec   = sumsq + FD;                   // [128]
    float* pooled = cvec + FD;                    // [G,128]
    float* t1     = pooled + (size_t)G * FD;      // [G,256]
    float* t2     = t1 + (size_t)G * 256;         // [G,128]
    int*   degcnt = (int*)(t2 + (size_t)G * FD);  // [N]
    int*   offs   = degcnt + N;                   // [N+1] (padded to N+2)
    int*   cur    = offs + (N + 2);               // [N]
    int*   bsum   = cur + N;                      // [256]
    int2*  epak   = (int2*)(bsum + 256);          // [E] (dst, ee-weight)

    const int* srcp = adj;
    const int* dstp = adj + E;

    const int NB = (N + 255) / 256;

    // ---- CSR build (once; reused by all 3 layers) — XCD-partitioned
    hipMemsetAsync(degcnt, 0, (size_t)N * sizeof(int), stream);
    count_deg_part_k<<<8 * 392, 256, 0, stream>>>(srcp, degcnt, E);
    scan1_k<<<NB, 256, 0, stream>>>(degcnt, bsum, N);
    scan2_k<<<1, 256, 0, stream>>>(bsum, NB);
    scan3_k<<<NB, 256, 0, stream>>>(degcnt, bsum, offs, cur, N);
    fill_csr_part_k<<<8 * 392, 256, 0, stream>>>(srcp, dstp, cur, epak, E);
    init_affine_k<<<1, 128, 0, stream>>>(scale, shift, sums, sumsq);
    cvt_in_k<<<(N * FD / 4 + 255) / 256, 256, 0, stream>>>(xin, Xb, N * FD / 4);

    const int gemm_grid = (N + 63) / 64;
    const int wave_grid = (N + 3) / 4;      // 4 waves per 256-thread block
    const float invN = 1.0f / (float)N;

    // ---- layer 1 (identity affine folded into Wt)
    wprep_k<<<FD, 128, 0, stream>>>(W1, scale, shift, Wt, cvec);
    gemm_mfma_k<<<gemm_grid, 256, 0, stream>>>(Xb, Wt, cvec, a1, Hb, es, ed, N);
    ee_k<<<wave_grid, 256, 0, stream>>>(es, ed, offs, epak, rowsum, N);
    agg_k<<<wave_grid, 256, 0, stream>>>(Hb, rowsum, offs, epak, Xb, buf1, 0, N);
    bnstats_b_k<<<256, 256, 0, stream>>>(Xb, sums, sumsq, N);
    bnfinal_k<<<1, 128, 0, stream>>>(sums, sumsq, bn2g, bn2b, scale, shift, invN);

    // ---- layer 2 (BN folded into Wt/cvec)
    wprep_k<<<FD, 128, 0, stream>>>(W2, scale, shift, Wt, cvec);
    gemm_mfma_k<<<gemm_grid, 256, 0, stream>>>(Xb, Wt, cvec, a2, Hb, es, ed, N);
    ee_k<<<wave_grid, 256, 0, stream>>>(es, ed, offs, epak, rowsum, N);
    agg_k<<<wave_grid, 256, 0, stream>>>(Hb, rowsum, offs, epak, Xb, buf1, 0, N);
    bnstats_b_k<<<256, 256, 0, stream>>>(Xb, sums, sumsq, N);
    bnfinal_k<<<1, 128, 0, stream>>>(sums, sumsq, bn3g, bn3b, scale, shift, invN);

    // ---- layer 3 (fp32 agg out for pooling)
    wprep_k<<<FD, 128, 0, stream>>>(W3, scale, shift, Wt, cvec);
    gemm_mfma_k<<<gemm_grid, 256, 0, stream>>>(Xb, Wt, cvec, a3, Hb, es, ed, N);
    ee_k<<<wave_grid, 256, 0, stream>>>(es, ed, offs, epak, rowsum, N);
    agg_k<<<wave_grid, 256, 0, stream>>>(Hb, rowsum, offs, epak, Xb, buf1, 1, N);

    // ---- pooling + MLP
    hipMemsetAsync(pooled, 0, (size_t)G * FD * sizeof(float), stream);
    pool_k<<<(N + 127) / 128, 256, 0, stream>>>(buf1, gi, pooled, N);
    fc_relu_k<<<G, 256, FD * sizeof(float), stream>>>(pooled, fc1w, fc1b, t1, FD, 256);
    fc_relu_k<<<G, 128, 256 * sizeof(float), stream>>>(t1, fc2w, fc2b, t2, 256, FD);
    fc3_k<<<G, 64, 0, stream>>>(t2, fc3w, fc3b, out);
}

// Round 8
// 459.332 us; speedup vs baseline: 1.4228x; 1.0759x over previous
//
#include <hip/hip_runtime.h>
#include <hip/hip_bf16.h>

#define N_NODES 50000
#define N_EDGES 800000
#define FD 128
#define N_GRAPHS 256
#define NPART 6250   // N_NODES / 8 (nodes per XCD partition)

typedef unsigned short u16;
typedef short bf16x8 __attribute__((ext_vector_type(8)));
typedef float f32x4 __attribute__((ext_vector_type(4)));

__device__ __forceinline__ u16 f2bf(float v) {
    __hip_bfloat16 h = __float2bfloat16(v);
    union { __hip_bfloat16 hh; u16 u; } c; c.hh = h; return c.u;
}
__device__ __forceinline__ float bf2f(u16 r) {
    return __uint_as_float(((unsigned int)r) << 16);
}

// ---------------------------------------------------------------- CSR build (XCD-partitioned)
__global__ __launch_bounds__(256) void count_deg_part_k(const int* __restrict__ src,
                                                        int* __restrict__ cnt, int E) {
    int part = blockIdx.x & 7;
    int lo = part * NPART, hi = lo + NPART;
    int stride = (gridDim.x >> 3) * 256;
    for (int e = (blockIdx.x >> 3) * 256 + threadIdx.x; e < E; e += stride) {
        int s = src[e];
        if (s >= lo && s < hi) atomicAdd(&cnt[s], 1);
    }
}

__global__ __launch_bounds__(256) void fill_csr_part_k(const int* __restrict__ src,
                                                       const int* __restrict__ dst,
                                                       int* __restrict__ cur,
                                                       int* __restrict__ edst, int E) {
    int part = blockIdx.x & 7;
    int lo = part * NPART, hi = lo + NPART;
    int stride = (gridDim.x >> 3) * 256;
    for (int e = (blockIdx.x >> 3) * 256 + threadIdx.x; e < E; e += stride) {
        int s = src[e];
        if (s >= lo && s < hi) {
            int p = atomicAdd(&cur[s], 1);
            edst[p] = dst[e];
        }
    }
}

__global__ __launch_bounds__(256) void scan1_k(const int* __restrict__ cnt,
                                               int* __restrict__ bsum, int M) {
    int i = blockIdx.x * 256 + threadIdx.x;
    int v = (i < M) ? cnt[i] : 0;
    __shared__ int l[256];
    l[threadIdx.x] = v;
    __syncthreads();
    for (int s = 128; s > 0; s >>= 1) {
        if (threadIdx.x < s) l[threadIdx.x] += l[threadIdx.x + s];
        __syncthreads();
    }
    if (threadIdx.x == 0) bsum[blockIdx.x] = l[0];
}

__global__ __launch_bounds__(256) void scan2_k(int* __restrict__ bsum, int NB) {
    int tid = threadIdx.x;
    int v = (tid < NB) ? bsum[tid] : 0;
    __shared__ int l[256];
    l[tid] = v;
    __syncthreads();
    for (int off = 1; off < 256; off <<= 1) {
        int t = (tid >= off) ? l[tid - off] : 0;
        __syncthreads();
        l[tid] += t;
        __syncthreads();
    }
    if (tid < NB) bsum[tid] = l[tid] - v;   // exclusive
}

__global__ __launch_bounds__(256) void scan3_k(const int* __restrict__ cnt,
                                               const int* __restrict__ bsum,
                                               int* __restrict__ offs,
                                               int* __restrict__ cur, int M) {
    int i = blockIdx.x * 256 + threadIdx.x;
    int tid = threadIdx.x;
    int v = (i < M) ? cnt[i] : 0;
    __shared__ int l[256];
    l[tid] = v;
    __syncthreads();
    for (int off = 1; off < 256; off <<= 1) {
        int t = (tid >= off) ? l[tid - off] : 0;
        __syncthreads();
        l[tid] += t;
        __syncthreads();
    }
    int excl = l[tid] - v + bsum[blockIdx.x];
    if (i < M) { offs[i] = excl; cur[i] = excl; }
    if (i == M - 1) offs[M] = excl + v;
}

// ---------------------------------------------------------------- input fp32 -> bf16
__global__ __launch_bounds__(256) void cvt_in_k(const float* __restrict__ X,
                                                u16* __restrict__ Xb, int n4) {
    int i = blockIdx.x * 256 + threadIdx.x;
    if (i < n4) {
        float4 v = ((const float4*)X)[i];
        ushort4 o;
        o.x = f2bf(v.x); o.y = f2bf(v.y); o.z = f2bf(v.z); o.w = f2bf(v.w);
        ((ushort4*)Xb)[i] = o;
    }
}

// ---------------------------------------------------------------- per-layer weight prep
// Wt[n][k] = bf16(scale[k]*W[k][n]);  cvec[n] = sum_k shift[k]*W[k][n]
__global__ __launch_bounds__(128) void wprep_k(const float* __restrict__ W,
                                               const float* __restrict__ scale,
                                               const float* __restrict__ shift,
                                               u16* __restrict__ Wt,
                                               float* __restrict__ cvec) {
    int n = blockIdx.x, k = threadIdx.x;
    float w = W[(size_t)k * FD + n];
    Wt[(size_t)n * FD + k] = f2bf(scale[k] * w);
    __shared__ float l[128];
    l[k] = shift[k] * w;
    __syncthreads();
    for (int s = 64; s > 0; s >>= 1) {
        if (k < s) l[k] += l[k + s];
        __syncthreads();
    }
    if (k == 0) cvec[n] = l[0];
}

// ---------------------------------------------------------------- MFMA GEMM + dots
// H[m][n] = sum_k Xb[m][k]*Wt[n][k] + cvec[n] ; es/ed = H @ a ; H stored bf16.
// BM=64 rows/block, 4 waves x (16 rows x 128 cols), mfma_f32_16x16x32_bf16.
__global__ __launch_bounds__(256) void gemm_mfma_k(const u16* __restrict__ Xb,
                                                   const u16* __restrict__ Wt,
                                                   const float* __restrict__ cvec,
                                                   const float* __restrict__ avec,
                                                   u16* __restrict__ Hb,
                                                   float* __restrict__ es,
                                                   float* __restrict__ ed, int M) {
    __shared__ u16 As[64][136];   // +8 pad: 2-way bank alias only
    __shared__ u16 Bs[128][136];
    __shared__ float sa_s[128], sa_d[128], cv[128];
    int tid = threadIdx.x;
    if (tid < 128) { sa_s[tid] = avec[tid]; sa_d[tid] = avec[128 + tid]; cv[tid] = cvec[tid]; }
    int row0 = blockIdx.x * 64;
    // stage B (Wt is [n][k] bf16, dense): thread t -> n=t>>1, k0=(t&1)*64
    {
        int n = tid >> 1, k0 = (tid & 1) * 64;
        const uint4* s = (const uint4*)(Wt + (size_t)n * FD + k0);
#pragma unroll
        for (int u = 0; u < 8; u++) *(uint4*)&Bs[n][k0 + u * 8] = s[u];
    }
    // stage A: thread t -> r=t>>2, k0=(t&3)*32
    {
        int r = tid >> 2, k0 = (tid & 3) * 32;
        int grow = row0 + r;
        if (grow < M) {
            const uint4* s = (const uint4*)(Xb + (size_t)grow * FD + k0);
#pragma unroll
            for (int u = 0; u < 4; u++) *(uint4*)&As[r][k0 + u * 8] = s[u];
        } else {
            uint4 z = make_uint4(0, 0, 0, 0);
#pragma unroll
            for (int u = 0; u < 4; u++) *(uint4*)&As[r][k0 + u * 8] = z;
        }
    }
    __syncthreads();

    int wave = tid >> 6, lane = tid & 63;
    int quad = lane >> 4, n16 = lane & 15;
    int rbase = wave * 16;
    f32x4 acc[8];
    f32x4 zz = {0.f, 0.f, 0.f, 0.f};
#pragma unroll
    for (int t = 0; t < 8; t++) acc[t] = zz;

#pragma unroll
    for (int kk = 0; kk < 128; kk += 32) {
        bf16x8 a = *(const bf16x8*)&As[rbase + n16][kk + quad * 8];
#pragma unroll
        for (int t = 0; t < 8; t++) {
            bf16x8 b = *(const bf16x8*)&Bs[t * 16 + n16][kk + quad * 8];
            acc[t] = __builtin_amdgcn_mfma_f32_16x16x32_bf16(a, b, acc[t], 0, 0, 0);
        }
    }

    // epilogue: +cvec, attention dots (butterfly over the 16 lanes of each quad), bf16 store
#pragma unroll
    for (int reg = 0; reg < 4; reg++) {
        int grow = row0 + rbase + quad * 4 + reg;
        float vals[8];
        float ps = 0.f, pd = 0.f;
#pragma unroll
        for (int t = 0; t < 8; t++) {
            float v = acc[t][reg] + cv[t * 16 + n16];
            vals[t] = v;
            ps += v * sa_s[t * 16 + n16];
            pd += v * sa_d[t * 16 + n16];
        }
#pragma unroll
        for (int o = 8; o > 0; o >>= 1) { ps += __shfl_xor(ps, o); pd += __shfl_xor(pd, o); }
        if (grow < M) {
            if (n16 == 0) { es[grow] = ps; ed[grow] = pd; }
#pragma unroll
            for (int t = 0; t < 8; t++)
                Hb[(size_t)grow * FD + t * 16 + n16] = f2bf(vals[t]);
        }
    }
}

// ---------------------------------------------------------------- fused aggregation
// wave per node; edge stream + ed gathers on the SCALAR pipe (all wave-uniform);
// ee = exp(-leaky(es+ed)) computed redundantly in VALU; vector pipe does only
// the 64-lane bf16 row gather + FMA.
__global__ __launch_bounds__(256) void agg_k(const u16* __restrict__ Hb,
                                             const float* __restrict__ es_,
                                             const float* __restrict__ ed_,
                                             const int* __restrict__ offs,
                                             const int* __restrict__ edst,
                                             u16* __restrict__ OutB,
                                             float* __restrict__ OutF,
                                             int fp32out, int M) {
    int node = __builtin_amdgcn_readfirstlane((int)((blockIdx.x * blockDim.x + threadIdx.x) >> 6));
    int lane = threadIdx.x & 63;
    if (node >= M) return;
    int s0 = offs[node], s1 = offs[node + 1];
    float esv = es_[node];
    const unsigned int* Hrow = (const unsigned int*)Hb;   // one dword = bf16x2 per lane
    float2 a0 = make_float2(0.f, 0.f), a1 = make_float2(0.f, 0.f);
    float2 a2 = make_float2(0.f, 0.f), a3 = make_float2(0.f, 0.f);
    float rs = 0.f;
    int e = s0;
    for (; e + 8 <= s1; e += 8) {
        int d[8];
#pragma unroll
        for (int u = 0; u < 8; u++) d[u] = __builtin_amdgcn_readfirstlane(edst[e + u]);
        float w[8];
#pragma unroll
        for (int u = 0; u < 8; u++) {
            float ev = esv + ed_[d[u]];
            float lr = ev > 0.f ? ev : 0.2f * ev;
            w[u] = __expf(-lr);
        }
        unsigned int r[8];
#pragma unroll
        for (int u = 0; u < 8; u++) r[u] = Hrow[(size_t)d[u] * 64 + lane];
#pragma unroll
        for (int u = 0; u < 8; u++) {
            rs += w[u];
            float2* ac = (u & 3) == 0 ? &a0 : (u & 3) == 1 ? &a1 : (u & 3) == 2 ? &a2 : &a3;
            ac->x += w[u] * __int_as_float(r[u] << 16);
            ac->y += w[u] * __int_as_float(r[u] & 0xffff0000u);
        }
    }
    for (; e < s1; e++) {
        int d = __builtin_amdgcn_readfirstlane(edst[e]);
        float ev = esv + ed_[d];
        float lr = ev > 0.f ? ev : 0.2f * ev;
        float wv = __expf(-lr);
        rs += wv;
        unsigned int r = Hrow[(size_t)d * 64 + lane];
        a0.x += wv * __int_as_float(r << 16);
        a0.y += wv * __int_as_float(r & 0xffff0000u);
    }
    float inv = 1.f / (rs + 1e-16f);
    float vx = (a0.x + a1.x + a2.x + a3.x) * inv;
    float vy = (a0.y + a1.y + a2.y + a3.y) * inv;
    vx = vx > 0.f ? vx : (__expf(vx) - 1.f);   // elu, alpha=1
    vy = vy > 0.f ? vy : (__expf(vy) - 1.f);
    if (fp32out) {
        ((float2*)OutF)[(size_t)node * 64 + lane] = make_float2(vx, vy);
    } else {
        unsigned int pk = ((unsigned int)f2bf(vy) << 16) | f2bf(vx);
        ((unsigned int*)OutB)[(size_t)node * 64 + lane] = pk;
    }
}

// ---------------------------------------------------------------- BN stats (bf16 input) / finalize
__global__ void bnstats_b_k(const u16* __restrict__ Xb, float* __restrict__ sums,
                            float* __restrict__ sumsq, int M) {
    int f = threadIdx.x & 127;
    int half = threadIdx.x >> 7;
    float s1 = 0.f, s2 = 0.f;
    for (int r = blockIdx.x * 2 + half; r < M; r += gridDim.x * 2) {
        float v = bf2f(Xb[(size_t)r * FD + f]);
        s1 += v; s2 += v * v;
    }
    __shared__ float l1[256], l2[256];
    l1[threadIdx.x] = s1; l2[threadIdx.x] = s2;
    __syncthreads();
    if (half == 0) {
        atomicAdd(&sums[f], l1[f] + l1[f + 128]);
        atomicAdd(&sumsq[f], l2[f] + l2[f + 128]);
    }
}

__global__ void init_affine_k(float* scale, float* shift, float* sums, float* sumsq) {
    int f = threadIdx.x;
    scale[f] = 1.f; shift[f] = 0.f; sums[f] = 0.f; sumsq[f] = 0.f;
}

__global__ void bnfinal_k(float* sums, float* sumsq, const float* __restrict__ g,
                          const float* __restrict__ b, float* scale, float* shift, float invN) {
    int f = threadIdx.x;
    float mu = sums[f] * invN;
    float var = sumsq[f] * invN - mu * mu;
    float sc = g[f] * rsqrtf(var + 1e-5f);
    scale[f] = sc;
    shift[f] = b[f] - mu * sc;
    sums[f] = 0.f; sumsq[f] = 0.f;   // ready for next stats pass
}

// ---------------------------------------------------------------- pooling (sorted graph ids)
__global__ void pool_k(const float* __restrict__ X, const int* __restrict__ gi,
                       float* __restrict__ pooled, int M) {
    int f = threadIdx.x & 127;
    int half = threadIdx.x >> 7;
    int r0 = blockIdx.x * 128 + half;
    int rend = min(blockIdx.x * 128 + 128, M);
    int curg = -1; float acc = 0.f;
    for (int r = r0; r < rend; r += 2) {
        int g = gi[r];
        if (g != curg) {
            if (curg >= 0) atomicAdd(&pooled[(size_t)curg * FD + f], acc);
            curg = g; acc = 0.f;
        }
        acc += X[(size_t)r * FD + f];
    }
    if (curg >= 0) atomicAdd(&pooled[(size_t)curg * FD + f], acc);
}

// ---------------------------------------------------------------- small MLP
__global__ void fc_relu_k(const float* __restrict__ X, const float* __restrict__ Wt,
                          const float* __restrict__ b, float* __restrict__ Y,
                          int K, int Ncols) {
    int g = blockIdx.x;
    int j = threadIdx.x;
    extern __shared__ float xrow[];
    for (int k = threadIdx.x; k < K; k += blockDim.x) xrow[k] = X[(size_t)g * K + k];
    __syncthreads();
    float s = b[j];
    for (int k = 0; k < K; k++) s += xrow[k] * Wt[(size_t)k * Ncols + j];
    Y[(size_t)g * Ncols + j] = fmaxf(s, 0.f);
}

__global__ void fc3_k(const float* __restrict__ X, const float* __restrict__ W,
                      const float* __restrict__ b, float* __restrict__ out) {
    int g = blockIdx.x;
    int l = threadIdx.x;
    float2 x2 = ((const float2*)X)[g * 64 + l];
    float s0 = x2.x * W[(2 * l) * 2]     + x2.y * W[(2 * l + 1) * 2];
    float s1 = x2.x * W[(2 * l) * 2 + 1] + x2.y * W[(2 * l + 1) * 2 + 1];
#pragma unroll
    for (int o = 32; o > 0; o >>= 1) { s0 += __shfl_xor(s0, o); s1 += __shfl_xor(s1, o); }
    if (l == 0) { out[g * 2] = s0 + b[0]; out[g * 2 + 1] = s1 + b[1]; }
}

// ---------------------------------------------------------------- launcher
extern "C" void kernel_launch(void* const* d_in, const int* in_sizes, int n_in,
                              void* d_out, int out_size, void* d_ws, size_t ws_size,
                              hipStream_t stream) {
    const int*   adj  = (const int*)d_in[0];
    const float* xin  = (const float*)d_in[1];
    const int*   gi   = (const int*)d_in[2];
    const float* W1   = (const float*)d_in[4];
    const float* a1   = (const float*)d_in[5];
    const float* bn2g = (const float*)d_in[6];
    const float* bn2b = (const float*)d_in[7];
    const float* W2   = (const float*)d_in[8];
    const float* a2   = (const float*)d_in[9];
    const float* bn3g = (const float*)d_in[10];
    const float* bn3b = (const float*)d_in[11];
    const float* W3   = (const float*)d_in[12];
    const float* a3   = (const float*)d_in[13];
    const float* fc1w = (const float*)d_in[14];
    const float* fc1b = (const float*)d_in[15];
    const float* fc2w = (const float*)d_in[16];
    const float* fc2b = (const float*)d_in[17];
    const float* fc3w = (const float*)d_in[18];
    const float* fc3b = (const float*)d_in[19];
    float* out = (float*)d_out;

    const int N = N_NODES, E = N_EDGES, G = N_GRAPHS;

    float* buf1   = (float*)d_ws;                 // [N,128] fp32 (layer-3 agg out / pool in)
    u16*   Xb     = (u16*)(buf1 + (size_t)N * FD);   // [N,128] bf16 node features
    u16*   Hb     = Xb + (size_t)N * FD;             // [N,128] bf16 post-GEMM
    u16*   Wt     = Hb + (size_t)N * FD;             // [128,128] bf16 transposed, BN-folded
    float* es     = (float*)(Wt + FD * FD);       // [N]
    float* ed     = es + N;                       // [N]
    float* scale  = ed + N;                       // [128]
    float* shift  = scale + FD;                   // [128]
    float* sums   = shift + FD;                   // [128]
    float* sumsq  = sums + FD;                    // [128]
    float* cvec   = sumsq + FD;                   // [128]
    float* pooled = cvec + FD;                    // [G,128]
    float* t1     = pooled + (size_t)G * FD;      // [G,256]
    float* t2     = t1 + (size_t)G * 256;         // [G,128]
    int*   degcnt = (int*)(t2 + (size_t)G * FD);  // [N]
    int*   offs   = degcnt + N;                   // [N+1] (padded to N+2)
    int*   cur    = offs + (N + 2);               // [N]
    int*   bsum   = cur + N;                      // [256]
    int*   edst   = bsum + 256;                   // [E] dst per CSR slot

    const int* srcp = adj;
    const int* dstp = adj + E;

    const int NB = (N + 255) / 256;

    // ---- CSR build (once; reused by all 3 layers) — XCD-partitioned
    hipMemsetAsync(degcnt, 0, (size_t)N * sizeof(int), stream);
    count_deg_part_k<<<8 * 392, 256, 0, stream>>>(srcp, degcnt, E);
    scan1_k<<<NB, 256, 0, stream>>>(degcnt, bsum, N);
    scan2_k<<<1, 256, 0, stream>>>(bsum, NB);
    scan3_k<<<NB, 256, 0, stream>>>(degcnt, bsum, offs, cur, N);
    fill_csr_part_k<<<8 * 392, 256, 0, stream>>>(srcp, dstp, cur, edst, E);
    init_affine_k<<<1, 128, 0, stream>>>(scale, shift, sums, sumsq);
    cvt_in_k<<<(N * FD / 4 + 255) / 256, 256, 0, stream>>>(xin, Xb, N * FD / 4);

    const int gemm_grid = (N + 63) / 64;
    const int wave_grid = (N + 3) / 4;      // 4 waves per 256-thread block
    const float invN = 1.0f / (float)N;

    // ---- layer 1 (identity affine folded into Wt)
    wprep_k<<<FD, 128, 0, stream>>>(W1, scale, shift, Wt, cvec);
    gemm_mfma_k<<<gemm_grid, 256, 0, stream>>>(Xb, Wt, cvec, a1, Hb, es, ed, N);
    agg_k<<<wave_grid, 256, 0, stream>>>(Hb, es, ed, offs, edst, Xb, buf1, 0, N);
    bnstats_b_k<<<256, 256, 0, stream>>>(Xb, sums, sumsq, N);
    bnfinal_k<<<1, 128, 0, stream>>>(sums, sumsq, bn2g, bn2b, scale, shift, invN);

    // ---- layer 2 (BN folded into Wt/cvec)
    wprep_k<<<FD, 128, 0, stream>>>(W2, scale, shift, Wt, cvec);
    gemm_mfma_k<<<gemm_grid, 256, 0, stream>>>(Xb, Wt, cvec, a2, Hb, es, ed, N);
    agg_k<<<wave_grid, 256, 0, stream>>>(Hb, es, ed, offs, edst, Xb, buf1, 0, N);
    bnstats_b_k<<<256, 256, 0, stream>>>(Xb, sums, sumsq, N);
    bnfinal_k<<<1, 128, 0, stream>>>(sums, sumsq, bn3g, bn3b, scale, shift, invN);

    // ---- layer 3 (fp32 agg out for pooling)
    wprep_k<<<FD, 128, 0, stream>>>(W3, scale, shift, Wt, cvec);
    gemm_mfma_k<<<gemm_grid, 256, 0, stream>>>(Xb, Wt, cvec, a3, Hb, es, ed, N);
    agg_k<<<wave_grid, 256, 0, stream>>>(Hb, es, ed, offs, edst, Xb, buf1, 1, N);

    // ---- pooling + MLP
    hipMemsetAsync(pooled, 0, (size_t)G * FD * sizeof(float), stream);
    pool_k<<<(N + 127) / 128, 256, 0, stream>>>(buf1, gi, pooled, N);
    fc_relu_k<<<G, 256, FD * sizeof(float), stream>>>(pooled, fc1w, fc1b, t1, FD, 256);
    fc_relu_k<<<G, 128, 256 * sizeof(float), stream>>>(t1, fc2w, fc2b, t2, 256, FD);
    fc3_k<<<G, 64, 0, stream>>>(t2, fc3w, fc3b, out);
}

// Round 9
// 432.645 us; speedup vs baseline: 1.5106x; 1.0617x over previous
//
#include <hip/hip_runtime.h>
#include <hip/hip_bf16.h>

#define N_NODES 50000
#define N_EDGES 800000
#define FD 128
#define N_GRAPHS 256
#define NPART 6250   // N_NODES / 8 (nodes per XCD partition)

typedef unsigned short u16;
typedef short bf16x8 __attribute__((ext_vector_type(8)));
typedef float f32x4 __attribute__((ext_vector_type(4)));

__device__ __forceinline__ u16 f2bf(float v) {
    __hip_bfloat16 h = __float2bfloat16(v);
    union { __hip_bfloat16 hh; u16 u; } c; c.hh = h; return c.u;
}
__device__ __forceinline__ float bf2f(u16 r) {
    return __uint_as_float(((unsigned int)r) << 16);
}

// ---------------------------------------------------------------- CSR build (XCD-partitioned)
__global__ __launch_bounds__(256) void count_deg_part_k(const int* __restrict__ src,
                                                        int* __restrict__ cnt, int E) {
    int part = blockIdx.x & 7;
    int lo = part * NPART, hi = lo + NPART;
    int stride = (gridDim.x >> 3) * 256;
    for (int e = (blockIdx.x >> 3) * 256 + threadIdx.x; e < E; e += stride) {
        int s = src[e];
        if (s >= lo && s < hi) atomicAdd(&cnt[s], 1);
    }
}

__global__ __launch_bounds__(256) void fill_csr_part_k(const int* __restrict__ src,
                                                       const int* __restrict__ dst,
                                                       int* __restrict__ cur,
                                                       int* __restrict__ edst, int E) {
    int part = blockIdx.x & 7;
    int lo = part * NPART, hi = lo + NPART;
    int stride = (gridDim.x >> 3) * 256;
    for (int e = (blockIdx.x >> 3) * 256 + threadIdx.x; e < E; e += stride) {
        int s = src[e];
        if (s >= lo && s < hi) {
            int p = atomicAdd(&cur[s], 1);
            edst[p] = dst[e];
        }
    }
}

__global__ __launch_bounds__(256) void scan1_k(const int* __restrict__ cnt,
                                               int* __restrict__ bsum, int M) {
    int i = blockIdx.x * 256 + threadIdx.x;
    int v = (i < M) ? cnt[i] : 0;
    __shared__ int l[256];
    l[threadIdx.x] = v;
    __syncthreads();
    for (int s = 128; s > 0; s >>= 1) {
        if (threadIdx.x < s) l[threadIdx.x] += l[threadIdx.x + s];
        __syncthreads();
    }
    if (threadIdx.x == 0) bsum[blockIdx.x] = l[0];
}

// also zeroes the 4x128 BN-sum buffers (z[0..511])
__global__ __launch_bounds__(256) void scan2_k(int* __restrict__ bsum, int NB,
                                               float* __restrict__ z) {
    int tid = threadIdx.x;
    z[tid] = 0.f; z[tid + 256] = 0.f;
    int v = (tid < NB) ? bsum[tid] : 0;
    __shared__ int l[256];
    l[tid] = v;
    __syncthreads();
    for (int off = 1; off < 256; off <<= 1) {
        int t = (tid >= off) ? l[tid - off] : 0;
        __syncthreads();
        l[tid] += t;
        __syncthreads();
    }
    if (tid < NB) bsum[tid] = l[tid] - v;   // exclusive
}

__global__ __launch_bounds__(256) void scan3_k(const int* __restrict__ cnt,
                                               const int* __restrict__ bsum,
                                               int* __restrict__ offs,
                                               int* __restrict__ cur, int M) {
    int i = blockIdx.x * 256 + threadIdx.x;
    int tid = threadIdx.x;
    int v = (i < M) ? cnt[i] : 0;
    __shared__ int l[256];
    l[tid] = v;
    __syncthreads();
    for (int off = 1; off < 256; off <<= 1) {
        int t = (tid >= off) ? l[tid - off] : 0;
        __syncthreads();
        l[tid] += t;
        __syncthreads();
    }
    int excl = l[tid] - v + bsum[blockIdx.x];
    if (i < M) { offs[i] = excl; cur[i] = excl; }
    if (i == M - 1) offs[M] = excl + v;
}

// ---------------------------------------------------------------- weight prep
// layer 1 (no affine): Wt[n][k] = bf16(W[k][n]); cvec = 0
__global__ __launch_bounds__(128) void wprep1_k(const float* __restrict__ W,
                                                u16* __restrict__ Wt,
                                                float* __restrict__ cvec) {
    int n = blockIdx.x, k = threadIdx.x;
    Wt[(size_t)n * FD + k] = f2bf(W[(size_t)k * FD + n]);
    if (k == 0) cvec[n] = 0.f;
}

// layers 2/3: BN finalize (redundant per block, from sums/sumsq) + weight fold
__global__ __launch_bounds__(128) void bnfw_k(const float* __restrict__ W,
                                              const float* __restrict__ sums,
                                              const float* __restrict__ sumsq,
                                              const float* __restrict__ g,
                                              const float* __restrict__ b,
                                              float invN,
                                              u16* __restrict__ Wt,
                                              float* __restrict__ cvec) {
    int n = blockIdx.x, k = threadIdx.x;
    __shared__ float scs[128], shs[128], l[128];
    float mu = sums[k] * invN;
    float var = sumsq[k] * invN - mu * mu;
    float sc = g[k] * rsqrtf(var + 1e-5f);
    scs[k] = sc;
    shs[k] = b[k] - mu * sc;
    __syncthreads();
    float w = W[(size_t)k * FD + n];
    Wt[(size_t)n * FD + k] = f2bf(scs[k] * w);
    l[k] = shs[k] * w;
    __syncthreads();
    for (int s = 64; s > 0; s >>= 1) {
        if (k < s) l[k] += l[k + s];
        __syncthreads();
    }
    if (k == 0) cvec[n] = l[0];
}

// ---------------------------------------------------------------- MFMA GEMM + dots
// H[m][n] = sum_k X[m][k]*Wt[n][k] + cvec[n] ; es/ed = H @ a ; H stored bf16.
// BM=64 rows/block, 4 waves x (16 rows x 128 cols), mfma_f32_16x16x32_bf16.
// use_f32: stage A from fp32 Xf (layer 1), else from bf16 Xb.
__global__ __launch_bounds__(256) void gemm_mfma_k(const float* __restrict__ Xf,
                                                   const u16* __restrict__ Xb,
                                                   int use_f32,
                                                   const u16* __restrict__ Wt,
                                                   const float* __restrict__ cvec,
                                                   const float* __restrict__ avec,
                                                   u16* __restrict__ Hb,
                                                   float* __restrict__ es,
                                                   float* __restrict__ ed, int M) {
    __shared__ u16 As[64][136];   // +8 pad: 2-way bank alias only
    __shared__ u16 Bs[128][136];
    __shared__ float sa_s[128], sa_d[128], cv[128];
    int tid = threadIdx.x;
    if (tid < 128) { sa_s[tid] = avec[tid]; sa_d[tid] = avec[128 + tid]; cv[tid] = cvec[tid]; }
    int row0 = blockIdx.x * 64;
    // stage B (Wt is [n][k] bf16, dense): thread t -> n=t>>1, k0=(t&1)*64
    {
        int n = tid >> 1, k0 = (tid & 1) * 64;
        const uint4* s = (const uint4*)(Wt + (size_t)n * FD + k0);
#pragma unroll
        for (int u = 0; u < 8; u++) *(uint4*)&Bs[n][k0 + u * 8] = s[u];
    }
    // stage A: thread t -> r=t>>2, k0=(t&3)*32
    {
        int r = tid >> 2, k0 = (tid & 3) * 32;
        int grow = row0 + r;
        if (grow < M) {
            if (use_f32) {
                const float4* s = (const float4*)(Xf + (size_t)grow * FD + k0);
#pragma unroll
                for (int u = 0; u < 8; u++) {
                    float4 v = s[u];
                    ushort4 o;
                    o.x = f2bf(v.x); o.y = f2bf(v.y); o.z = f2bf(v.z); o.w = f2bf(v.w);
                    *(ushort4*)&As[r][k0 + u * 4] = o;
                }
            } else {
                const uint4* s = (const uint4*)(Xb + (size_t)grow * FD + k0);
#pragma unroll
                for (int u = 0; u < 4; u++) *(uint4*)&As[r][k0 + u * 8] = s[u];
            }
        } else {
            uint4 z = make_uint4(0, 0, 0, 0);
#pragma unroll
            for (int u = 0; u < 4; u++) *(uint4*)&As[r][k0 + u * 8] = z;
        }
    }
    __syncthreads();

    int wave = tid >> 6, lane = tid & 63;
    int quad = lane >> 4, n16 = lane & 15;
    int rbase = wave * 16;
    f32x4 acc[8];
    f32x4 zz = {0.f, 0.f, 0.f, 0.f};
#pragma unroll
    for (int t = 0; t < 8; t++) acc[t] = zz;

#pragma unroll
    for (int kk = 0; kk < 128; kk += 32) {
        bf16x8 a = *(const bf16x8*)&As[rbase + n16][kk + quad * 8];
#pragma unroll
        for (int t = 0; t < 8; t++) {
            bf16x8 b = *(const bf16x8*)&Bs[t * 16 + n16][kk + quad * 8];
            acc[t] = __builtin_amdgcn_mfma_f32_16x16x32_bf16(a, b, acc[t], 0, 0, 0);
        }
    }

    // epilogue: +cvec, attention dots (butterfly over the 16 lanes of each quad), bf16 store
#pragma unroll
    for (int reg = 0; reg < 4; reg++) {
        int grow = row0 + rbase + quad * 4 + reg;
        float vals[8];
        float ps = 0.f, pd = 0.f;
#pragma unroll
        for (int t = 0; t < 8; t++) {
            float v = acc[t][reg] + cv[t * 16 + n16];
            vals[t] = v;
            ps += v * sa_s[t * 16 + n16];
            pd += v * sa_d[t * 16 + n16];
        }
#pragma unroll
        for (int o = 8; o > 0; o >>= 1) { ps += __shfl_xor(ps, o); pd += __shfl_xor(pd, o); }
        if (grow < M) {
            if (n16 == 0) { es[grow] = ps; ed[grow] = pd; }
#pragma unroll
            for (int t = 0; t < 8; t++)
                Hb[(size_t)grow * FD + t * 16 + n16] = f2bf(vals[t]);
        }
    }
}

// ---------------------------------------------------------------- fused aggregation
// wave per node; edge stream + ed gathers on the SCALAR pipe (all wave-uniform);
// ee = exp(-leaky(es+ed)) computed redundantly in VALU; vector pipe does only
// the 64-lane bf16 row gather + FMA.  Output bf16.
__global__ __launch_bounds__(256) void agg_k(const u16* __restrict__ Hb,
                                             const float* __restrict__ es_,
                                             const float* __restrict__ ed_,
                                             const int* __restrict__ offs,
                                             const int* __restrict__ edst,
                                             u16* __restrict__ Out, int M) {
    int node = __builtin_amdgcn_readfirstlane((int)((blockIdx.x * blockDim.x + threadIdx.x) >> 6));
    int lane = threadIdx.x & 63;
    if (node >= M) return;
    int s0 = offs[node], s1 = offs[node + 1];
    float esv = es_[node];
    const unsigned int* Hrow = (const unsigned int*)Hb;   // one dword = bf16x2 per lane
    float2 a0 = make_float2(0.f, 0.f), a1 = make_float2(0.f, 0.f);
    float2 a2 = make_float2(0.f, 0.f), a3 = make_float2(0.f, 0.f);
    float rs = 0.f;
    int e = s0;
    for (; e + 8 <= s1; e += 8) {
        int d[8];
#pragma unroll
        for (int u = 0; u < 8; u++) d[u] = __builtin_amdgcn_readfirstlane(edst[e + u]);
        float w[8];
#pragma unroll
        for (int u = 0; u < 8; u++) {
            float ev = esv + ed_[d[u]];
            float lr = ev > 0.f ? ev : 0.2f * ev;
            w[u] = __expf(-lr);
        }
        unsigned int r[8];
#pragma unroll
        for (int u = 0; u < 8; u++) r[u] = Hrow[(size_t)d[u] * 64 + lane];
#pragma unroll
        for (int u = 0; u < 8; u++) {
            rs += w[u];
            float2* ac = (u & 3) == 0 ? &a0 : (u & 3) == 1 ? &a1 : (u & 3) == 2 ? &a2 : &a3;
            ac->x += w[u] * __int_as_float(r[u] << 16);
            ac->y += w[u] * __int_as_float(r[u] & 0xffff0000u);
        }
    }
    for (; e < s1; e++) {
        int d = __builtin_amdgcn_readfirstlane(edst[e]);
        float ev = esv + ed_[d];
        float lr = ev > 0.f ? ev : 0.2f * ev;
        float wv = __expf(-lr);
        rs += wv;
        unsigned int r = Hrow[(size_t)d * 64 + lane];
        a0.x += wv * __int_as_float(r << 16);
        a0.y += wv * __int_as_float(r & 0xffff0000u);
    }
    float inv = 1.f / (rs + 1e-16f);
    float vx = (a0.x + a1.x + a2.x + a3.x) * inv;
    float vy = (a0.y + a1.y + a2.y + a3.y) * inv;
    vx = vx > 0.f ? vx : (__expf(vx) - 1.f);   // elu, alpha=1
    vy = vy > 0.f ? vy : (__expf(vy) - 1.f);
    unsigned int pk = ((unsigned int)f2bf(vy) << 16) | f2bf(vx);
    ((unsigned int*)Out)[(size_t)node * 64 + lane] = pk;
}

// ---------------------------------------------------------------- BN stats (bf16 input)
__global__ void bnstats_b_k(const u16* __restrict__ Xb, float* __restrict__ sums,
                            float* __restrict__ sumsq, int M) {
    int f = threadIdx.x & 127;
    int half = threadIdx.x >> 7;
    float s1 = 0.f, s2 = 0.f;
    for (int r = blockIdx.x * 2 + half; r < M; r += gridDim.x * 2) {
        float v = bf2f(Xb[(size_t)r * FD + f]);
        s1 += v; s2 += v * v;
    }
    __shared__ float l1[256], l2[256];
    l1[threadIdx.x] = s1; l2[threadIdx.x] = s2;
    __syncthreads();
    if (half == 0) {
        atomicAdd(&sums[f], l1[f] + l1[f + 128]);
        atomicAdd(&sumsq[f], l2[f] + l2[f + 128]);
    }
}

// ---------------------------------------------------------------- pooling (sorted graph ids, bf16 in)
__global__ void pool_k(const u16* __restrict__ Xb, const int* __restrict__ gi,
                       float* __restrict__ pooled, int M) {
    int f = threadIdx.x & 127;
    int half = threadIdx.x >> 7;
    int r0 = blockIdx.x * 128 + half;
    int rend = min(blockIdx.x * 128 + 128, M);
    int curg = -1; float acc = 0.f;
    for (int r = r0; r < rend; r += 2) {
        int g = gi[r];
        if (g != curg) {
            if (curg >= 0) atomicAdd(&pooled[(size_t)curg * FD + f], acc);
            curg = g; acc = 0.f;
        }
        acc += bf2f(Xb[(size_t)r * FD + f]);
    }
    if (curg >= 0) atomicAdd(&pooled[(size_t)curg * FD + f], acc);
}

// ---------------------------------------------------------------- fused MLP (one block per graph)
__global__ __launch_bounds__(256) void mlp_k(const float* __restrict__ pooled,
                                             const float* __restrict__ fc1w, const float* __restrict__ fc1b,
                                             const float* __restrict__ fc2w, const float* __restrict__ fc2b,
                                             const float* __restrict__ fc3w, const float* __restrict__ fc3b,
                                             float* __restrict__ out) {
    int g = blockIdx.x, j = threadIdx.x;
    __shared__ float x[128], t1[256], t2[128], p0[128], p1[128];
    if (j < 128) x[j] = pooled[(size_t)g * FD + j];
    __syncthreads();
    float s = fc1b[j];
    for (int k = 0; k < 128; k++) s += x[k] * fc1w[(size_t)k * 256 + j];
    t1[j] = fmaxf(s, 0.f);
    __syncthreads();
    if (j < 128) {
        float s2 = fc2b[j];
        for (int k = 0; k < 256; k++) s2 += t1[k] * fc2w[(size_t)k * 128 + j];
        t2[j] = fmaxf(s2, 0.f);
    }
    __syncthreads();
    if (j < 128) { p0[j] = t2[j] * fc3w[j * 2]; p1[j] = t2[j] * fc3w[j * 2 + 1]; }
    __syncthreads();
    for (int s3 = 64; s3 > 0; s3 >>= 1) {
        if (j < s3) { p0[j] += p0[j + s3]; p1[j] += p1[j + s3]; }
        __syncthreads();
    }
    if (j == 0) { out[g * 2] = p0[0] + fc3b[0]; out[g * 2 + 1] = p1[0] + fc3b[1]; }
}

// ---------------------------------------------------------------- launcher
extern "C" void kernel_launch(void* const* d_in, const int* in_sizes, int n_in,
                              void* d_out, int out_size, void* d_ws, size_t ws_size,
                              hipStream_t stream) {
    const int*   adj  = (const int*)d_in[0];
    const float* xin  = (const float*)d_in[1];
    const int*   gi   = (const int*)d_in[2];
    const float* W1   = (const float*)d_in[4];
    const float* a1   = (const float*)d_in[5];
    const float* bn2g = (const float*)d_in[6];
    const float* bn2b = (const float*)d_in[7];
    const float* W2   = (const float*)d_in[8];
    const float* a2   = (const float*)d_in[9];
    const float* bn3g = (const float*)d_in[10];
    const float* bn3b = (const float*)d_in[11];
    const float* W3   = (const float*)d_in[12];
    const float* a3   = (const float*)d_in[13];
    const float* fc1w = (const float*)d_in[14];
    const float* fc1b = (const float*)d_in[15];
    const float* fc2w = (const float*)d_in[16];
    const float* fc2b = (const float*)d_in[17];
    const float* fc3w = (const float*)d_in[18];
    const float* fc3b = (const float*)d_in[19];
    float* out = (float*)d_out;

    const int N = N_NODES, E = N_EDGES, G = N_GRAPHS;

    u16*   Xb     = (u16*)d_ws;                   // [N,128] bf16 node features
    u16*   Hb     = Xb + (size_t)N * FD;          // [N,128] bf16 post-GEMM
    u16*   Wt     = Hb + (size_t)N * FD;          // [128,128] bf16 transposed, BN-folded
    float* es     = (float*)(Wt + FD * FD);       // [N]
    float* ed     = es + N;                       // [N]
    float* bnbuf  = ed + N;                       // [512]: sumsA, sumsqA, sumsB, sumsqB
    float* sumsA  = bnbuf;
    float* sumsqA = bnbuf + 128;
    float* sumsB  = bnbuf + 256;
    float* sumsqB = bnbuf + 384;
    float* cvec   = bnbuf + 512;                  // [128]
    float* pooled = cvec + FD;                    // [G,128]
    int*   degcnt = (int*)(pooled + (size_t)G * FD); // [N]
    int*   offs   = degcnt + N;                   // [N+1] (padded to N+2)
    int*   cur    = offs + (N + 2);               // [N]
    int*   bsum   = cur + N;                      // [256]
    int*   edst   = bsum + 256;                   // [E] dst per CSR slot

    const int* srcp = adj;
    const int* dstp = adj + E;

    const int NB = (N + 255) / 256;

    // ---- CSR build (once; reused by all 3 layers) — XCD-partitioned
    hipMemsetAsync(degcnt, 0, (size_t)N * sizeof(int), stream);
    count_deg_part_k<<<8 * 392, 256, 0, stream>>>(srcp, degcnt, E);
    scan1_k<<<NB, 256, 0, stream>>>(degcnt, bsum, N);
    scan2_k<<<1, 256, 0, stream>>>(bsum, NB, bnbuf);
    scan3_k<<<NB, 256, 0, stream>>>(degcnt, bsum, offs, cur, N);
    fill_csr_part_k<<<8 * 392, 256, 0, stream>>>(srcp, dstp, cur, edst, E);

    const int gemm_grid = (N + 63) / 64;
    const int wave_grid = (N + 3) / 4;      // 4 waves per 256-thread block
    const float invN = 1.0f / (float)N;

    // ---- layer 1 (fp32 input staged directly; identity affine)
    wprep1_k<<<FD, 128, 0, stream>>>(W1, Wt, cvec);
    gemm_mfma_k<<<gemm_grid, 256, 0, stream>>>(xin, Xb, 1, Wt, cvec, a1, Hb, es, ed, N);
    agg_k<<<wave_grid, 256, 0, stream>>>(Hb, es, ed, offs, edst, Xb, N);
    bnstats_b_k<<<256, 256, 0, stream>>>(Xb, sumsA, sumsqA, N);

    // ---- layer 2 (BN folded into Wt/cvec)
    bnfw_k<<<FD, 128, 0, stream>>>(W2, sumsA, sumsqA, bn2g, bn2b, invN, Wt, cvec);
    gemm_mfma_k<<<gemm_grid, 256, 0, stream>>>(nullptr, Xb, 0, Wt, cvec, a2, Hb, es, ed, N);
    agg_k<<<wave_grid, 256, 0, stream>>>(Hb, es, ed, offs, edst, Xb, N);
    bnstats_b_k<<<256, 256, 0, stream>>>(Xb, sumsB, sumsqB, N);

    // ---- layer 3
    bnfw_k<<<FD, 128, 0, stream>>>(W3, sumsB, sumsqB, bn3g, bn3b, invN, Wt, cvec);
    gemm_mfma_k<<<gemm_grid, 256, 0, stream>>>(nullptr, Xb, 0, Wt, cvec, a3, Hb, es, ed, N);
    agg_k<<<wave_grid, 256, 0, stream>>>(Hb, es, ed, offs, edst, Xb, N);

    // ---- pooling + MLP
    hipMemsetAsync(pooled, 0, (size_t)G * FD * sizeof(float), stream);
    pool_k<<<(N + 127) / 128, 256, 0, stream>>>(Xb, gi, pooled, N);
    mlp_k<<<G, 256, 0, stream>>>(pooled, fc1w, fc1b, fc2w, fc2b, fc3w, fc3b, out);
}